// Round 7
// baseline (3000.754 us; speedup 1.0000x reference)
//
#include <hip/hip_runtime.h>

typedef _Float16 h8 __attribute__((ext_vector_type(8)));
typedef _Float16 h4 __attribute__((ext_vector_type(4)));
typedef float f4 __attribute__((ext_vector_type(4)));
typedef unsigned int u32x4 __attribute__((ext_vector_type(4)));
typedef unsigned long long u64;
typedef unsigned int u32;

__device__ __forceinline__ float sigm(float x) { return 1.f / (1.f + __expf(-x)); }
__device__ __forceinline__ float tanhf_(float x) { return 1.f - 2.f / (1.f + __expf(2.f * x)); }

// ---------------------------------------------------------------------------
// pack_all: weights -> f16 fragment layout [gt][kc][lane][8],
// value(gt,kc,lane,i) = W[gt*16 + (lane&15)][kc*32 + ((lane>>4)<<3) + i] (0-pad).
// Same formula serves A-frags and B-frags (dim-index = lane&15, k-oct = lane>>4).
// biasc = b_ih + b_hh (f32).
// ---------------------------------------------------------------------------
__global__ __launch_bounds__(256) void pack_all(
    const float* __restrict__ wih0, const float* __restrict__ whh0,
    const float* __restrict__ wih1, const float* __restrict__ whh1,
    const float* __restrict__ wih2, const float* __restrict__ whh2,
    const float* __restrict__ bih0, const float* __restrict__ bhh0,
    const float* __restrict__ bih1, const float* __restrict__ bhh1,
    const float* __restrict__ bih2, const float* __restrict__ bhh2,
    _Float16* __restrict__ wihp0, _Float16* __restrict__ whhp0,
    _Float16* __restrict__ wihp1, _Float16* __restrict__ whhp1,
    _Float16* __restrict__ wihp2, _Float16* __restrict__ whhp2,
    float* __restrict__ biasc)
{
    if (blockIdx.x >= 324) {
        int bi = (blockIdx.x - 324) * 256 + threadIdx.x;
        if (bi < 1024)      biasc[bi] = bih0[bi] + bhh0[bi];
        else if (bi < 1280) biasc[bi] = bih1[bi - 1024] + bhh1[bi - 1024];
        else if (bi < 1536) biasc[bi] = bih2[bi - 1280] + bhh2[bi - 1280];
        return;
    }
    int s = blockIdx.x * 256 + threadIdx.x;
    const float* src; _Float16* dst; int KC, D;
    if (s < 40960)      {            dst = wihp0; src = wih0; KC = 10; D = 300; }
    else if (s < 73728) { s -= 40960; dst = whhp0; src = whh0; KC = 8;  D = 256; }
    else if (s < 76800) { s -= 73728; dst = wihp1; src = wih1; KC = 3;  D = 74;  }
    else if (s < 78848) { s -= 76800; dst = whhp1; src = whh1; KC = 2;  D = 64;  }
    else if (s < 80896) { s -= 78848; dst = wihp2; src = wih2; KC = 2;  D = 35;  }
    else                { s -= 80896; dst = whhp2; src = whh2; KC = 2;  D = 64;  }
    int lane = s & 63;
    int kc = (s >> 6) % KC;
    int gt = (s >> 6) / KC;
    int g = gt * 16 + (lane & 15);
    int kb = kc * 32 + ((lane >> 4) << 3);
    h8 v;
#pragma unroll
    for (int i = 0; i < 8; i++) {
        int k = kb + i;
        v[i] = (_Float16)((k < D) ? src[(size_t)g * D + k] : 0.f);
    }
    *(h8*)&dst[(size_t)s * 8] = v;
}

// ---------------------------------------------------------------------------
// xg phase: xg = x @ w_ih^T + bias (f16), pre-packed for the recurrence.
// LSTM0 (transposed C): xgp0[tc][grp(16)][s(4)][w2(8)][lane(64)][16],
//   idx = ga*4+q holds xg^T[gate-row][batch col] per rec fragment layout.
// LSTM1/2: [tc][bq(8)][w(8)][fp(4)][lane(64)][8]
// NOTE: axf padded to 96KB: LDS>80KB -> 1 block/CU -> compiler register
// target 256 VGPR (else acc[4][8] is over the 128-target and spills).
// ---------------------------------------------------------------------------
template <int M>
__device__ __forceinline__ void xg_block(int tc, int bq, int t0,
    const float* __restrict__ x, const _Float16* __restrict__ wihp,
    const float* __restrict__ bias, _Float16* __restrict__ xgp, _Float16* axf)
{
    constexpr int D   = (M == 0) ? 300 : ((M == 1) ? 74 : 35);
    constexpr int KCX = (M == 0) ? 10 : ((M == 1) ? 3 : 2);
    const int t = t0 + tc;
    const int tid = threadIdx.x, w = tid >> 6, l = tid & 63, ccol = l & 15;
    const int r0 = bq * 64;

    // stage A tile (64 rows x KCX*32 k) as f16 frags in LDS
    for (int sI = tid; sI < 4 * KCX * 64; sI += 512) {
        int rt = sI / (KCX * 64);
        int kc = (sI >> 6) % KCX;
        int ll = sI & 63;
        int row = r0 + rt * 16 + (ll & 15);
        int kb = kc * 32 + ((ll >> 4) << 3);
        const float* bp = x + ((size_t)row * 128 + t) * D + kb;
        h8 v;
#pragma unroll
        for (int i = 0; i < 8; i++) v[i] = (_Float16)((kb + i < D) ? bp[i] : 0.f);
        *(h8*)&axf[sI * 8] = v;
    }
    __syncthreads();

    if (M == 0) {
        // transposed: mfma(A = w_ih frag, B = x frag) -> C[gate][batch]
        f4 acc[4][8];
#pragma unroll
        for (int g = 0; g < 8; g++) {
            int gt = (g >> 1) * 16 + 2 * w + (g & 1);
            f4 bv4 = *(const f4*)&bias[gt * 16 + (l >> 4) * 4];
#pragma unroll
            for (int rt = 0; rt < 4; rt++) acc[rt][g] = bv4;
        }
#pragma unroll
        for (int kc = 0; kc < KCX; kc++) {
            h8 a[4];
#pragma unroll
            for (int rt = 0; rt < 4; rt++) a[rt] = *(const h8*)&axf[((rt * KCX + kc) * 64 + l) * 8];
#pragma unroll
            for (int g = 0; g < 8; g++) {
                int gt = (g >> 1) * 16 + 2 * w + (g & 1);
                h8 b = *(const h8*)&wihp[((size_t)(gt * KCX + kc) * 64 + l) * 8];
#pragma unroll
                for (int rt = 0; rt < 4; rt++)
                    acc[rt][g] = __builtin_amdgcn_mfma_f32_16x16x32_f16(b, a[rt], acc[rt][g], 0, 0, 0);
            }
        }
#pragma unroll
        for (int rt = 0; rt < 4; rt++) {
#pragma unroll
            for (int g = 0; g < 8; g++) {
                int e = 2 * w + (g & 1);
                int ga = g >> 1;
                int sx = e >> 2, q4v = e & 3;
                int grp = bq * 2 + (rt >> 1);
                int w2 = (rt & 1) * 4 + q4v;
                f4 a = acc[rt][g];
                h4 v;
#pragma unroll
                for (int q = 0; q < 4; q++) v[q] = (_Float16)a[q];
                size_t off = (size_t)tc * 524288 +
                             ((((size_t)grp * 4 + sx) * 8 + w2) * 64 + l) * 16 + ga * 4;
                *(h4*)&xgp[off] = v;
            }
        }
    } else {
        const int rh = w >> 2, ht = w & 3;
        f4 acc[2][4];
#pragma unroll
        for (int ga = 0; ga < 4; ga++) {
            int gt = ga * 4 + ht;
            float b = bias[gt * 16 + ccol];
            acc[0][ga] = (f4){b, b, b, b};
            acc[1][ga] = (f4){b, b, b, b};
        }
#pragma unroll
        for (int kc = 0; kc < KCX; kc++) {
            h8 a[2];
#pragma unroll
            for (int rr = 0; rr < 2; rr++)
                a[rr] = *(const h8*)&axf[(((rh * 2 + rr) * KCX + kc) * 64 + l) * 8];
#pragma unroll
            for (int ga = 0; ga < 4; ga++) {
                int gt = ga * 4 + ht;
                h8 b = *(const h8*)&wihp[((size_t)(gt * KCX + kc) * 64 + l) * 8];
#pragma unroll
                for (int rr = 0; rr < 2; rr++)
                    acc[rr][ga] = __builtin_amdgcn_mfma_f32_16x16x32_f16(a[rr], b, acc[rr][ga], 0, 0, 0);
            }
        }
#pragma unroll
        for (int rr = 0; rr < 2; rr++)
#pragma unroll
        for (int gp = 0; gp < 2; gp++) {
            f4 lo = acc[rr][2 * gp], hi = acc[rr][2 * gp + 1];
            h8 v;
#pragma unroll
            for (int q = 0; q < 4; q++) { v[q] = (_Float16)lo[q]; v[4 + q] = (_Float16)hi[q]; }
            int fp = rr * 2 + gp;
            size_t off = ((((size_t)tc * 8 + bq) * 8 + w) * 4 + fp) * 64 + l;
            *(h8*)&xgp[off * 8] = v;
        }
    }
}

__global__ __launch_bounds__(512, 1) void xg_kernel(
    const float* __restrict__ x0, const float* __restrict__ x1, const float* __restrict__ x2,
    const _Float16* __restrict__ wihp0, const _Float16* __restrict__ wihp1,
    const _Float16* __restrict__ wihp2, const float* __restrict__ biasc,
    _Float16* __restrict__ xgp0, _Float16* __restrict__ xgp1, _Float16* __restrict__ xgp2,
    int t0, int TC)
{
    // 96KB (pad): force 1 block/CU so the register target is 256 VGPR.
    __shared__ __align__(16) _Float16 axf[49152];
    int b = blockIdx.x;
    int per = TC * 8;
    if (b < per)            xg_block<0>(b >> 3, b & 7, t0, x0, wihp0, biasc,        xgp0, axf);
    else if (b < 2 * per) { b -= per;     xg_block<1>(b >> 3, b & 7, t0, x1, wihp1, biasc + 1024, xgp1, axf); }
    else                  { b -= 2 * per; xg_block<2>(b >> 3, b & 7, t0, x2, wihp2, biasc + 1280, xgp2, axf); }
}

// ---------------------------------------------------------------------------
// Recurrence. Grid = 32 blocks x 512 threads.
//  bid 0-15: LSTM0. slice s = bid&3 (64 h-cols), superblock g4 = bid>>2
//            (4 groups of 32 batch rows, time-multiplexed per step).
//            w_hh slice lives in REGISTERS (128 VGPR/thread).
//            REGISTER-TARGET MECHANISM (rounds 5/6 post-mortem): the AMDGPU
//            allocator targets max occupancy achievable given LDS. At 64KB
//            LDS, 2 blocks/CU fit -> 128-VGPR target -> wreg gets
//            REMATERIALIZED from L2 every phase (= streaming, 2.9ms).
//            Fix: pad LDS to 96KB -> 1 block/CU -> 256-VGPR target; plus
//            asm opacity on wreg to forbid rematerialization.
//            Per phase j: prepare apack[j+1] (poll tag + gather), MFMA gatesT
//            for group j, in-register cell update, publish one u64/lane +
//            per-wave release tag. One barrier per phase; exchange has a
//            3-phase latency window.
//  bid 16-23: LSTM1. 24-31: LSTM2. (LDS-resident)
// ---------------------------------------------------------------------------
__global__ __launch_bounds__(512, 1) void rec_kernel(
    const _Float16* __restrict__ whhp0, const _Float16* __restrict__ whhp1,
    const _Float16* __restrict__ whhp2,
    const _Float16* __restrict__ xgp0, const _Float16* __restrict__ xgp1,
    const _Float16* __restrict__ xgp2,
    float* __restrict__ h_all, float* __restrict__ csave, _Float16* __restrict__ hsave,
    u64* __restrict__ hx, u32* __restrict__ tags,
    int t0, int TC)
{
    __shared__ __align__(16) char smem[98304];   // 96KB pad (see note above)
    const int bid = blockIdx.x;
    const int tid = threadIdx.x, w = tid >> 6, l = tid & 63;
    const int ccol = l & 15, crow = (l >> 4) * 4;

    if (bid < 16) {
        // ----- LSTM0 -----
        const int g4 = bid >> 2, s = bid & 3;
        const int bt = w >> 2, q4 = w & 3;
        const int sp1 = (s + 1) & 3, sp2 = (s + 2) & 3, sp3 = (s + 3) & 3;
        u64* ap = (u64*)smem;  // [4 groups][32 rows][64 chunks] u64, chunk XOR-swizzled

        // w_hh slice -> registers: A-frags for gt = ga*16 + s*4 + q4
        h8 wreg[4][8];
#pragma unroll
        for (int ga = 0; ga < 4; ga++)
#pragma unroll
            for (int kc = 0; kc < 8; kc++)
                wreg[ga][kc] = *(const h8*)&whhp0[((size_t)(((ga * 16 + s * 4 + q4) * 8 + kc) * 64) + l) * 8];
        // opacity: values become asm results -> cannot be rematerialized from
        // memory by the register allocator (round-6 failure mode).
#pragma unroll
        for (int ga = 0; ga < 4; ga++)
#pragma unroll
            for (int kc = 0; kc < 8; kc++)
                asm volatile("" : "+v"(wreg[ga][kc]));

        const int myrow = bt * 16 + (l & 15);
        const int mcb = q4 * 4 + (l >> 4);       // in-slice chunk (h-col/4)
        const int swz = (myrow & 7) << 1;
        float c[4][4];
        u64 ownh[4];
        float* cs = csave + ((size_t)bid * 512 + tid) * 16;

        if (t0 == 0) {
#pragma unroll
            for (int j = 0; j < 4; j++) {
                ownh[j] = 0ULL;
#pragma unroll
                for (int q = 0; q < 4; q++) c[j][q] = 0.f;
            }
            for (int v = tid; v < 8192; v += 512) ap[v] = 0ULL;
        } else {
#pragma unroll
            for (int j = 0; j < 4; j++) {
                const int grp = g4 * 4 + j;
                const u32 tv = (u32)t0;
                const u32* tg = &tags[((size_t)((t0 - 1) * 16 + grp) * 4) * 8];
                while (true) {
                    u32 a0 = __hip_atomic_load(&tg[s * 8 + w],   __ATOMIC_ACQUIRE, __HIP_MEMORY_SCOPE_AGENT);
                    u32 a1 = __hip_atomic_load(&tg[sp1 * 8 + w], __ATOMIC_ACQUIRE, __HIP_MEMORY_SCOPE_AGENT);
                    u32 a2 = __hip_atomic_load(&tg[sp2 * 8 + w], __ATOMIC_ACQUIRE, __HIP_MEMORY_SCOPE_AGENT);
                    u32 a3 = __hip_atomic_load(&tg[sp3 * 8 + w], __ATOMIC_ACQUIRE, __HIP_MEMORY_SCOPE_AGENT);
                    if (a0 == tv && a1 == tv && a2 == tv && a3 == tv) break;
                }
                const u64* hb = &hx[((size_t)((t0 - 1) * 16 + grp) * 4) * 512];
                u64 d0 = __hip_atomic_load(&hb[s * 512 + tid],   __ATOMIC_RELAXED, __HIP_MEMORY_SCOPE_AGENT);
                u64 d1 = __hip_atomic_load(&hb[sp1 * 512 + tid], __ATOMIC_RELAXED, __HIP_MEMORY_SCOPE_AGENT);
                u64 d2 = __hip_atomic_load(&hb[sp2 * 512 + tid], __ATOMIC_RELAXED, __HIP_MEMORY_SCOPE_AGENT);
                u64 d3 = __hip_atomic_load(&hb[sp3 * 512 + tid], __ATOMIC_RELAXED, __HIP_MEMORY_SCOPE_AGENT);
                ap[(size_t)j * 2048 + myrow * 64 + ((s * 16 + mcb) ^ swz)]   = d0;
                ap[(size_t)j * 2048 + myrow * 64 + ((sp1 * 16 + mcb) ^ swz)] = d1;
                ap[(size_t)j * 2048 + myrow * 64 + ((sp2 * 16 + mcb) ^ swz)] = d2;
                ap[(size_t)j * 2048 + myrow * 64 + ((sp3 * 16 + mcb) ^ swz)] = d3;
                ownh[j] = d0;
#pragma unroll
                for (int q = 0; q < 4; q++) c[j][q] = cs[j * 4 + q];
            }
        }
        __syncthreads();

        // prologue xg load: group g4*4+0, tc=0
        const size_t xg_l16 = (size_t)l * 16;
        h8 xcur0 = *(const h8*)&xgp0[((((size_t)(g4 * 4 + 0) * 4 + s) * 8 + w) * 64) * 16 + xg_l16];
        h8 xcur1 = *(const h8*)&xgp0[((((size_t)(g4 * 4 + 0) * 4 + s) * 8 + w) * 64) * 16 + xg_l16 + 8];

        for (int tc = 0; tc < TC; tc++) {
            const int t = t0 + tc;
#pragma unroll
            for (int j = 0; j < 4; j++) {
                const int grp = g4 * 4 + j;
                const int jn = (j + 1) & 3, grpn = g4 * 4 + jn;
                const int src_t = (j == 3) ? t : (t - 1);
                const int tgt_tc = (j == 3) ? (tc + 1) : tc;
                const bool do_xg = (tgt_tc < TC);
                const bool do_gather = do_xg && (src_t >= 0);

                h8 xn0 = xcur0, xn1 = xcur1;
                if (do_xg) {
                    const size_t xb = (size_t)tgt_tc * 524288 +
                                      ((((size_t)grpn * 4 + s) * 8 + w) * 64) * 16 + xg_l16;
                    xn0 = *(const h8*)&xgp0[xb];
                    xn1 = *(const h8*)&xgp0[xb + 8];
                }
                u64 d1 = 0, d2 = 0, d3 = 0;
                if (do_gather) {
                    const u32 tv = (u32)(src_t + 1);
                    const u32* tg = &tags[((size_t)(src_t * 16 + grpn) * 4) * 8];
                    while (true) {
                        u32 a1 = __hip_atomic_load(&tg[sp1 * 8 + w], __ATOMIC_ACQUIRE, __HIP_MEMORY_SCOPE_AGENT);
                        u32 a2 = __hip_atomic_load(&tg[sp2 * 8 + w], __ATOMIC_ACQUIRE, __HIP_MEMORY_SCOPE_AGENT);
                        u32 a3 = __hip_atomic_load(&tg[sp3 * 8 + w], __ATOMIC_ACQUIRE, __HIP_MEMORY_SCOPE_AGENT);
                        if (a1 == tv && a2 == tv && a3 == tv) break;
                    }
                    const u64* hb = &hx[((size_t)(src_t * 16 + grpn) * 4) * 512];
                    d1 = __hip_atomic_load(&hb[sp1 * 512 + tid], __ATOMIC_RELAXED, __HIP_MEMORY_SCOPE_AGENT);
                    d2 = __hip_atomic_load(&hb[sp2 * 512 + tid], __ATOMIC_RELAXED, __HIP_MEMORY_SCOPE_AGENT);
                    d3 = __hip_atomic_load(&hb[sp3 * 512 + tid], __ATOMIC_RELAXED, __HIP_MEMORY_SCOPE_AGENT);
                }

                // gates^T = xg + W_slice @ h^T
                f4 acc[4];
#pragma unroll
                for (int q = 0; q < 4; q++) {
                    acc[0][q] = (float)xcur0[q];
                    acc[1][q] = (float)xcur0[4 + q];
                    acc[2][q] = (float)xcur1[q];
                    acc[3][q] = (float)xcur1[4 + q];
                }
#pragma unroll
                for (int kc = 0; kc < 8; kc++) {
                    int cp = (kc * 8 + (l >> 4) * 2) ^ swz;
                    h8 bv = *(const h8*)&ap[(size_t)j * 2048 + myrow * 64 + cp];
#pragma unroll
                    for (int ga = 0; ga < 4; ga++)
                        acc[ga] = __builtin_amdgcn_mfma_f32_16x16x32_f16(wreg[ga][kc], bv, acc[ga], 0, 0, 0);
                }

                // cell update: acc[ga][q] = gate ga, h-col q4*16+(l>>4)*4+q, batch row myrow
                float hv[4];
#pragma unroll
                for (int q = 0; q < 4; q++) {
                    float gi = acc[0][q], gf = acc[1][q], gg = acc[2][q], go = acc[3][q];
                    float cn = sigm(gf) * c[j][q] + sigm(gi) * tanhf_(gg);
                    c[j][q] = cn;
                    hv[q] = sigm(go) * tanhf_(cn);
                }
                if (t == 127) {
                    f4 o;
#pragma unroll
                    for (int q = 0; q < 4; q++) o[q] = hv[q];
                    *(f4*)&h_all[(size_t)(grp * 32 + myrow) * 384 + s * 64 + q4 * 16 + (l >> 4) * 4] = o;
                } else {
                    h4 hp;
#pragma unroll
                    for (int q = 0; q < 4; q++) hp[q] = (_Float16)hv[q];
                    u64 hu = *(u64*)&hp;
                    __hip_atomic_store(&hx[((size_t)(t * 16 + grp) * 4 + s) * 512 + tid], hu,
                                       __ATOMIC_RELAXED, __HIP_MEMORY_SCOPE_AGENT);
                    if (l == 0)
                        __hip_atomic_store(&tags[((size_t)(t * 16 + grp) * 4 + s) * 8 + w], (u32)(t + 1),
                                           __ATOMIC_RELEASE, __HIP_MEMORY_SCOPE_AGENT);
                    ownh[j] = hu;
                }
                if (do_gather) {
                    ap[(size_t)jn * 2048 + myrow * 64 + ((sp1 * 16 + mcb) ^ swz)] = d1;
                    ap[(size_t)jn * 2048 + myrow * 64 + ((sp2 * 16 + mcb) ^ swz)] = d2;
                    ap[(size_t)jn * 2048 + myrow * 64 + ((sp3 * 16 + mcb) ^ swz)] = d3;
                    ap[(size_t)jn * 2048 + myrow * 64 + ((s * 16 + mcb) ^ swz)]   = ownh[jn];
                }
                __syncthreads();
                xcur0 = xn0; xcur1 = xn1;
            }
        }
        if (t0 + TC < 128) {
#pragma unroll
            for (int j = 0; j < 4; j++)
#pragma unroll
                for (int q = 0; q < 4; q++) cs[j * 4 + q] = c[j][q];
        }
    } else {
        // ----- LSTM1 / LSTM2 (LDS-resident, unchanged structure) -----
        const int m = (bid < 24) ? 1 : 2;
        const int lb = (bid - 16) & 7;
        const int r0 = lb * 64;
        const int colb = (m == 1) ? 256 : 320;
        const _Float16* whhp = (m == 1) ? whhp1 : whhp2;
        const _Float16* xgp  = (m == 1) ? xgp1 : xgp2;
        _Float16* whhs = (_Float16*)smem;                 // 32 KB
        _Float16* apkA = (_Float16*)(smem + 32768);       // 8 KB
        _Float16* apkB = (_Float16*)(smem + 40960);       // 8 KB
        const int rh = w >> 2, ht = w & 3;
        float c[8];
        h8 xbuf[4];
        float* cs = csave + 131072 + (((size_t)(bid - 16)) * 512 + tid) * 8;
        for (int v = tid; v < 2048; v += 512) ((u32x4*)whhs)[v] = ((const u32x4*)whhp)[v];
        if (t0 == 0) {
#pragma unroll
            for (int i = 0; i < 8; i++) c[i] = 0.f;
            u32x4 z = (u32x4){0u, 0u, 0u, 0u};
            for (int v = tid; v < 512; v += 512) ((u32x4*)apkA)[v] = z;
        } else {
#pragma unroll
            for (int i = 0; i < 8; i++) c[i] = cs[i];
            const u32x4* hsrc = (const u32x4*)(hsave + (size_t)(bid - 16) * 4096);
            for (int v = tid; v < 512; v += 512) ((u32x4*)apkA)[v] = hsrc[v];
        }
        __syncthreads();

        const size_t xbase = ((size_t)lb * 8 + w) * 4 * 512 + (size_t)l * 8;
#pragma unroll
        for (int fp = 0; fp < 4; fp++)
            xbuf[fp] = *(const h8*)&xgp[xbase + (size_t)fp * 512];

        f4 acc[2][4];
        for (int tc = 0; tc < TC; tc++) {
            _Float16* cur = (tc & 1) ? apkB : apkA;
            _Float16* nxt = (tc & 1) ? apkA : apkB;
#pragma unroll
            for (int rr = 0; rr < 2; rr++)
#pragma unroll
            for (int gp = 0; gp < 2; gp++) {
                int fp = rr * 2 + gp;
#pragma unroll
                for (int q = 0; q < 4; q++) {
                    acc[rr][2 * gp][q]     = (float)xbuf[fp][q];
                    acc[rr][2 * gp + 1][q] = (float)xbuf[fp][4 + q];
                }
            }
            if (tc + 1 < TC) {
                size_t nb = xbase + (size_t)(tc + 1) * 8 * 8 * 4 * 512;
#pragma unroll
                for (int fp = 0; fp < 4; fp++)
                    xbuf[fp] = *(const h8*)&xgp[nb + (size_t)fp * 512];
            }
#pragma unroll
            for (int kc = 0; kc < 2; kc++) {
                h8 a0 = *(const h8*)&cur[(((rh * 2 + 0) * 2 + kc) * 64 + l) * 8];
                h8 a1 = *(const h8*)&cur[(((rh * 2 + 1) * 2 + kc) * 64 + l) * 8];
#pragma unroll
                for (int ga = 0; ga < 4; ga++) {
                    int gt = ga * 4 + ht;
                    h8 b = *(const h8*)&whhs[((gt * 2 + kc) * 64 + l) * 8];
                    acc[0][ga] = __builtin_amdgcn_mfma_f32_16x16x32_f16(a0, b, acc[0][ga], 0, 0, 0);
                    acc[1][ga] = __builtin_amdgcn_mfma_f32_16x16x32_f16(a1, b, acc[1][ga], 0, 0, 0);
                }
            }
            const int t = t0 + tc;
#pragma unroll
            for (int rr = 0; rr < 2; rr++)
#pragma unroll
            for (int q = 0; q < 4; q++) {
                int idx = rr * 4 + q;
                float gi = acc[rr][0][q];
                float gf = acc[rr][1][q];
                float gg = acc[rr][2][q];
                float go = acc[rr][3][q];
                float cn = sigm(gf) * c[idx] + sigm(gi) * tanhf_(gg);
                c[idx] = cn;
                float hv = sigm(go) * tanhf_(cn);
                int row = (rh * 2 + rr) * 16 + crow + q;
                int hcol = ht * 16 + ccol;
                if (t == 127) h_all[(size_t)(r0 + row) * 384 + colb + hcol] = hv;
                int kch = ht >> 1;
                int sub = (ht & 1) * 2 + (ccol >> 3);
                nxt[(((row >> 4) * 2 + kch) * 64 + sub * 16 + (row & 15)) * 8 + (ccol & 7)] = (_Float16)hv;
            }
            __syncthreads();
        }
        if (t0 + TC < 128) {
#pragma unroll
            for (int i = 0; i < 8; i++) cs[i] = c[i];
            u32x4* hdst = (u32x4*)(hsave + (size_t)(bid - 16) * 4096);
            const u32x4* src = (const u32x4*)((TC & 1) ? apkB : apkA);
            for (int v = tid; v < 512; v += 512) hdst[v] = src[v];
        }
    }
}

// ---------------------------------------------------------------------------
// MLP head (unchanged — verified)
// ---------------------------------------------------------------------------
__global__ __launch_bounds__(512) void mlp_kernel(const float* __restrict__ h_all,
                                                  const float* __restrict__ w1,
                                                  const float* __restrict__ b1,
                                                  const float* __restrict__ w2,
                                                  const float* __restrict__ b2,
                                                  float* __restrict__ out)
{
    __shared__ float w1s[64 * 385];
    __shared__ float hs[8 * 384];
    int tid = threadIdx.x;
    for (int idx = tid; idx < 64 * 384; idx += 512) {
        int j = idx / 384, k = idx - j * 384;
        w1s[j * 385 + k] = w1[idx];
    }
    int r0 = blockIdx.x * 8;
    for (int idx = tid; idx < 8 * 384; idx += 512) hs[idx] = h_all[(size_t)r0 * 384 + idx];
    __syncthreads();

    int w = tid >> 6, j = tid & 63;
    float accv = b1[j];
    const float* hrow = &hs[w * 384];
    for (int k = 0; k < 384; k++) accv = fmaf(hrow[k], w1s[j * 385 + k], accv);
    float hid = fmaxf(accv, 0.f);
    float v = hid * w2[j];
#pragma unroll
    for (int off = 32; off >= 1; off >>= 1) v += __shfl_xor(v, off, 64);
    if (j == 0) out[r0 + w] = v + b2[0];
}

// ---------------------------------------------------------------------------
extern "C" void kernel_launch(void* const* d_in, const int* in_sizes, int n_in,
                              void* d_out, int out_size, void* d_ws, size_t ws_size,
                              hipStream_t stream)
{
    const float* x0   = (const float*)d_in[0];
    const float* x1   = (const float*)d_in[1];
    const float* x2   = (const float*)d_in[2];
    const float* wih0 = (const float*)d_in[3];
    const float* whh0 = (const float*)d_in[4];
    const float* bih0 = (const float*)d_in[5];
    const float* bhh0 = (const float*)d_in[6];
    const float* wih1 = (const float*)d_in[7];
    const float* whh1 = (const float*)d_in[8];
    const float* bih1 = (const float*)d_in[9];
    const float* bhh1 = (const float*)d_in[10];
    const float* wih2 = (const float*)d_in[11];
    const float* whh2 = (const float*)d_in[12];
    const float* bih2 = (const float*)d_in[13];
    const float* bhh2 = (const float*)d_in[14];
    const float* w1   = (const float*)d_in[15];
    const float* b1   = (const float*)d_in[16];
    const float* w2   = (const float*)d_in[17];
    const float* b2   = (const float*)d_in[18];

    char* ws = (char*)d_ws;
    size_t off = 0;
    auto alloc = [&](size_t bytes) { size_t o = off; off = (off + bytes + 255) & ~255ULL; return o; };
    size_t o_wihp0 = alloc(655360);
    size_t o_whhp0 = alloc(524288);
    size_t o_wihp1 = alloc(49152);
    size_t o_whhp1 = alloc(32768);
    size_t o_wihp2 = alloc(32768);
    size_t o_whhp2 = alloc(32768);
    size_t o_bias  = alloc(6144);
    size_t o_hall  = alloc(786432);
    size_t o_csave = alloc(786432);
    size_t o_hsave = alloc(131072);
    size_t o_hx    = alloc(33554432);   // hx[128][16][4][512] u64 (4KB per slice)
    size_t o_tags  = alloc(262144);     // tags[128][16][4][8] u32
    size_t fixed = off;

    int TC = 128;
    while (TC > 1 && fixed + (size_t)TC * 1572864ULL + 1024 > ws_size) TC >>= 1;
    size_t o_xgp0 = alloc((size_t)TC * 1048576ULL);
    size_t o_xgp1 = alloc((size_t)TC * 262144ULL);
    size_t o_xgp2 = alloc((size_t)TC * 262144ULL);

    _Float16* wihp0 = (_Float16*)(ws + o_wihp0);
    _Float16* whhp0 = (_Float16*)(ws + o_whhp0);
    _Float16* wihp1 = (_Float16*)(ws + o_wihp1);
    _Float16* whhp1 = (_Float16*)(ws + o_whhp1);
    _Float16* wihp2 = (_Float16*)(ws + o_wihp2);
    _Float16* whhp2 = (_Float16*)(ws + o_whhp2);
    float*    biasc = (float*)(ws + o_bias);
    float*    hall  = (float*)(ws + o_hall);
    float*    csave = (float*)(ws + o_csave);
    _Float16* hsave = (_Float16*)(ws + o_hsave);
    u64*      hx    = (u64*)(ws + o_hx);
    u32*      tags  = (u32*)(ws + o_tags);
    _Float16* xgp0  = (_Float16*)(ws + o_xgp0);
    _Float16* xgp1  = (_Float16*)(ws + o_xgp1);
    _Float16* xgp2  = (_Float16*)(ws + o_xgp2);

    hipMemsetAsync(ws + o_tags, 0, 262144, stream);

    pack_all<<<330, 256, 0, stream>>>(wih0, whh0, wih1, whh1, wih2, whh2,
                                      bih0, bhh0, bih1, bhh1, bih2, bhh2,
                                      wihp0, whhp0, wihp1, whhp1, wihp2, whhp2, biasc);

    for (int t0 = 0; t0 < 128; t0 += TC) {
        xg_kernel<<<24 * TC, 512, 0, stream>>>(x0, x1, x2, wihp0, wihp1, wihp2, biasc,
                                               xgp0, xgp1, xgp2, t0, TC);
        rec_kernel<<<32, 512, 0, stream>>>(whhp0, whhp1, whhp2, xgp0, xgp1, xgp2,
                                           hall, csave, hsave, hx, tags, t0, TC);
    }

    mlp_kernel<<<64, 512, 0, stream>>>(hall, w1, b1, w2, b2, (float*)d_out);
}

// Round 8
// 2266.574 us; speedup vs baseline: 1.3239x; 1.3239x over previous
//
#include <hip/hip_runtime.h>

typedef _Float16 h8 __attribute__((ext_vector_type(8)));
typedef _Float16 h4 __attribute__((ext_vector_type(4)));
typedef float f4 __attribute__((ext_vector_type(4)));
typedef unsigned int u32x4 __attribute__((ext_vector_type(4)));
typedef unsigned long long u64;
typedef unsigned int u32;

__device__ __forceinline__ float sigm(float x) { return 1.f / (1.f + __expf(-x)); }
__device__ __forceinline__ float tanhf_(float x) { return 1.f - 2.f / (1.f + __expf(2.f * x)); }

// ---------------------------------------------------------------------------
// pack_all: weights -> f16 fragment layout [gt][kc][lane][8],
// value(gt,kc,lane,i) = W[gt*16 + (lane&15)][kc*32 + ((lane>>4)<<3) + i] (0-pad).
// biasc = b_ih + b_hh (f32).
// ---------------------------------------------------------------------------
__global__ __launch_bounds__(256) void pack_all(
    const float* __restrict__ wih0, const float* __restrict__ whh0,
    const float* __restrict__ wih1, const float* __restrict__ whh1,
    const float* __restrict__ wih2, const float* __restrict__ whh2,
    const float* __restrict__ bih0, const float* __restrict__ bhh0,
    const float* __restrict__ bih1, const float* __restrict__ bhh1,
    const float* __restrict__ bih2, const float* __restrict__ bhh2,
    _Float16* __restrict__ wihp0, _Float16* __restrict__ whhp0,
    _Float16* __restrict__ wihp1, _Float16* __restrict__ whhp1,
    _Float16* __restrict__ wihp2, _Float16* __restrict__ whhp2,
    float* __restrict__ biasc)
{
    if (blockIdx.x >= 324) {
        int bi = (blockIdx.x - 324) * 256 + threadIdx.x;
        if (bi < 1024)      biasc[bi] = bih0[bi] + bhh0[bi];
        else if (bi < 1280) biasc[bi] = bih1[bi - 1024] + bhh1[bi - 1024];
        else if (bi < 1536) biasc[bi] = bih2[bi - 1280] + bhh2[bi - 1280];
        return;
    }
    int s = blockIdx.x * 256 + threadIdx.x;
    const float* src; _Float16* dst; int KC, D;
    if (s < 40960)      {            dst = wihp0; src = wih0; KC = 10; D = 300; }
    else if (s < 73728) { s -= 40960; dst = whhp0; src = whh0; KC = 8;  D = 256; }
    else if (s < 76800) { s -= 73728; dst = wihp1; src = wih1; KC = 3;  D = 74;  }
    else if (s < 78848) { s -= 76800; dst = whhp1; src = whh1; KC = 2;  D = 64;  }
    else if (s < 80896) { s -= 78848; dst = wihp2; src = wih2; KC = 2;  D = 35;  }
    else                { s -= 80896; dst = whhp2; src = whh2; KC = 2;  D = 64;  }
    int lane = s & 63;
    int kc = (s >> 6) % KC;
    int gt = (s >> 6) / KC;
    int g = gt * 16 + (lane & 15);
    int kb = kc * 32 + ((lane >> 4) << 3);
    h8 v;
#pragma unroll
    for (int i = 0; i < 8; i++) {
        int k = kb + i;
        v[i] = (_Float16)((k < D) ? src[(size_t)g * D + k] : 0.f);
    }
    *(h8*)&dst[(size_t)s * 8] = v;
}

// ---------------------------------------------------------------------------
// xg phase: xg = x @ w_ih^T + bias (f16), pre-packed for the recurrence.
// LSTM0 (transposed C): xgp0[tc][grp(16)][s(4)][w2(8)][lane(64)][16].
// LSTM1/2: [tc][bq(8)][w(8)][fp(4)][lane(64)][8]
// amdgpu_waves_per_eu(2,2): pin the register-allocator budget to 256 VGPR
// (acc[4][8] = 128 f32 otherwise gets spilled to scratch — rounds 5-7 bug).
// ---------------------------------------------------------------------------
template <int M>
__device__ __forceinline__ void xg_block(int tc, int bq, int t0,
    const float* __restrict__ x, const _Float16* __restrict__ wihp,
    const float* __restrict__ bias, _Float16* __restrict__ xgp, _Float16* axf)
{
    constexpr int D   = (M == 0) ? 300 : ((M == 1) ? 74 : 35);
    constexpr int KCX = (M == 0) ? 10 : ((M == 1) ? 3 : 2);
    const int t = t0 + tc;
    const int tid = threadIdx.x, w = tid >> 6, l = tid & 63, ccol = l & 15;
    const int r0 = bq * 64;

    // stage A tile (64 rows x KCX*32 k) as f16 frags in LDS
    for (int sI = tid; sI < 4 * KCX * 64; sI += 512) {
        int rt = sI / (KCX * 64);
        int kc = (sI >> 6) % KCX;
        int ll = sI & 63;
        int row = r0 + rt * 16 + (ll & 15);
        int kb = kc * 32 + ((ll >> 4) << 3);
        const float* bp = x + ((size_t)row * 128 + t) * D + kb;
        h8 v;
#pragma unroll
        for (int i = 0; i < 8; i++) v[i] = (_Float16)((kb + i < D) ? bp[i] : 0.f);
        *(h8*)&axf[sI * 8] = v;
    }
    __syncthreads();

    if (M == 0) {
        // transposed: mfma(A = w_ih frag, B = x frag) -> C[gate][batch]
        f4 acc[4][8];
#pragma unroll
        for (int g = 0; g < 8; g++) {
            int gt = (g >> 1) * 16 + 2 * w + (g & 1);
            f4 bv4 = *(const f4*)&bias[gt * 16 + (l >> 4) * 4];
#pragma unroll
            for (int rt = 0; rt < 4; rt++) acc[rt][g] = bv4;
        }
#pragma unroll
        for (int kc = 0; kc < KCX; kc++) {
            h8 a[4];
#pragma unroll
            for (int rt = 0; rt < 4; rt++) a[rt] = *(const h8*)&axf[((rt * KCX + kc) * 64 + l) * 8];
#pragma unroll
            for (int g = 0; g < 8; g++) {
                int gt = (g >> 1) * 16 + 2 * w + (g & 1);
                h8 b = *(const h8*)&wihp[((size_t)(gt * KCX + kc) * 64 + l) * 8];
#pragma unroll
                for (int rt = 0; rt < 4; rt++)
                    acc[rt][g] = __builtin_amdgcn_mfma_f32_16x16x32_f16(b, a[rt], acc[rt][g], 0, 0, 0);
            }
        }
#pragma unroll
        for (int rt = 0; rt < 4; rt++) {
#pragma unroll
            for (int g = 0; g < 8; g++) {
                int e = 2 * w + (g & 1);
                int ga = g >> 1;
                int sx = e >> 2, q4v = e & 3;
                int grp = bq * 2 + (rt >> 1);
                int w2 = (rt & 1) * 4 + q4v;
                f4 a = acc[rt][g];
                h4 v;
#pragma unroll
                for (int q = 0; q < 4; q++) v[q] = (_Float16)a[q];
                size_t off = (size_t)tc * 524288 +
                             ((((size_t)grp * 4 + sx) * 8 + w2) * 64 + l) * 16 + ga * 4;
                *(h4*)&xgp[off] = v;
            }
        }
    } else {
        const int rh = w >> 2, ht = w & 3;
        f4 acc[2][4];
#pragma unroll
        for (int ga = 0; ga < 4; ga++) {
            int gt = ga * 4 + ht;
            float b = bias[gt * 16 + ccol];
            acc[0][ga] = (f4){b, b, b, b};
            acc[1][ga] = (f4){b, b, b, b};
        }
#pragma unroll
        for (int kc = 0; kc < KCX; kc++) {
            h8 a[2];
#pragma unroll
            for (int rr = 0; rr < 2; rr++)
                a[rr] = *(const h8*)&axf[(((rh * 2 + rr) * KCX + kc) * 64 + l) * 8];
#pragma unroll
            for (int ga = 0; ga < 4; ga++) {
                int gt = ga * 4 + ht;
                h8 b = *(const h8*)&wihp[((size_t)(gt * KCX + kc) * 64 + l) * 8];
#pragma unroll
                for (int rr = 0; rr < 2; rr++)
                    acc[rr][ga] = __builtin_amdgcn_mfma_f32_16x16x32_f16(a[rr], b, acc[rr][ga], 0, 0, 0);
            }
        }
#pragma unroll
        for (int rr = 0; rr < 2; rr++)
#pragma unroll
        for (int gp = 0; gp < 2; gp++) {
            f4 lo = acc[rr][2 * gp], hi = acc[rr][2 * gp + 1];
            h8 v;
#pragma unroll
            for (int q = 0; q < 4; q++) { v[q] = (_Float16)lo[q]; v[4 + q] = (_Float16)hi[q]; }
            int fp = rr * 2 + gp;
            size_t off = ((((size_t)tc * 8 + bq) * 8 + w) * 4 + fp) * 64 + l;
            *(h8*)&xgp[off * 8] = v;
        }
    }
}

__global__ __launch_bounds__(512) __attribute__((amdgpu_waves_per_eu(2, 2)))
void xg_kernel(
    const float* __restrict__ x0, const float* __restrict__ x1, const float* __restrict__ x2,
    const _Float16* __restrict__ wihp0, const _Float16* __restrict__ wihp1,
    const _Float16* __restrict__ wihp2, const float* __restrict__ biasc,
    _Float16* __restrict__ xgp0, _Float16* __restrict__ xgp1, _Float16* __restrict__ xgp2,
    int t0, int TC)
{
    // 96KB pad: 1 block/CU so 2 waves/EU is the true occupancy.
    __shared__ __align__(16) _Float16 axf[49152];
    int b = blockIdx.x;
    int per = TC * 8;
    if (b < per)            xg_block<0>(b >> 3, b & 7, t0, x0, wihp0, biasc,        xgp0, axf);
    else if (b < 2 * per) { b -= per;     xg_block<1>(b >> 3, b & 7, t0, x1, wihp1, biasc + 1024, xgp1, axf); }
    else                  { b -= 2 * per; xg_block<2>(b >> 3, b & 7, t0, x2, wihp2, biasc + 1280, xgp2, axf); }
}

// ---------------------------------------------------------------------------
// Recurrence. Grid = 32 blocks x 512 threads.
//  XCD-local mapping (bid%8 = XCD round-robin assumption; speed-only):
//   bid&7 < 4 : LSTM0 with g4 = bid&7, s = bid>>3  -> the 4 slice-peers of a
//               superblock are congruent mod 8 => same XCD => exchange via
//               the shared per-XCD L2 (visibility ~hundreds of cycles).
//   bid&7 >= 4: LSTM1/2, idx = (bid>>3)*4 + (bid&7) - 4 in 0..15.
//  LSTM0: slice s (64 h-cols), 4 batch groups of 32 rows time-multiplexed.
//   w_hh slice in REGISTERS (128 VGPR/thread). amdgpu_waves_per_eu(2,2) pins
//   the allocator budget at 256 VGPR (rounds 5-7: default target ~128 =>
//   wreg spilled to scratch => 2.9ms). asm opacity blocks rematerialization.
//   Spin-polls are RELAXED (acquire-in-loop = waitcnt+L1-inv per iteration;
//   relaxed atomics bypass L1 and hx is write-once/read-once per t — the
//   rounds-3/4-proven pattern). Tag store stays RELEASE (orders data first).
// ---------------------------------------------------------------------------
__global__ __launch_bounds__(512) __attribute__((amdgpu_waves_per_eu(2, 2)))
void rec_kernel(
    const _Float16* __restrict__ whhp0, const _Float16* __restrict__ whhp1,
    const _Float16* __restrict__ whhp2,
    const _Float16* __restrict__ xgp0, const _Float16* __restrict__ xgp1,
    const _Float16* __restrict__ xgp2,
    float* __restrict__ h_all, float* __restrict__ csave, _Float16* __restrict__ hsave,
    u64* __restrict__ hx, u32* __restrict__ tags,
    int t0, int TC)
{
    __shared__ __align__(16) char smem[98304];   // 96KB pad: 1 block/CU
    const int bid = blockIdx.x;
    const int tid = threadIdx.x, w = tid >> 6, l = tid & 63;
    const int ccol = l & 15, crow = (l >> 4) * 4;
    const int r8 = bid & 7, hi8 = bid >> 3;

    if (r8 < 4) {
        // ----- LSTM0 -----
        const int g4 = r8, s = hi8;
        const int lid0 = g4 * 4 + s;             // logical block id 0..15
        const int bt = w >> 2, q4 = w & 3;
        const int sp1 = (s + 1) & 3, sp2 = (s + 2) & 3, sp3 = (s + 3) & 3;
        u64* ap = (u64*)smem;  // [4 groups][32 rows][64 chunks] u64, XOR-swizzled

        // w_hh slice -> registers: A-frags for gt = ga*16 + s*4 + q4
        h8 wreg[4][8];
#pragma unroll
        for (int ga = 0; ga < 4; ga++)
#pragma unroll
            for (int kc = 0; kc < 8; kc++)
                wreg[ga][kc] = *(const h8*)&whhp0[((size_t)(((ga * 16 + s * 4 + q4) * 8 + kc) * 64) + l) * 8];
        // opacity: forbid rematerialization of the weight fragments.
#pragma unroll
        for (int ga = 0; ga < 4; ga++)
#pragma unroll
            for (int kc = 0; kc < 8; kc++)
                asm volatile("" : "+v"(wreg[ga][kc]));

        const int myrow = bt * 16 + (l & 15);
        const int mcb = q4 * 4 + (l >> 4);       // in-slice chunk (h-col/4)
        const int swz = (myrow & 7) << 1;
        float c[4][4];
        u64 ownh[4];
        float* cs = csave + ((size_t)lid0 * 512 + tid) * 16;

        if (t0 == 0) {
#pragma unroll
            for (int j = 0; j < 4; j++) {
                ownh[j] = 0ULL;
#pragma unroll
                for (int q = 0; q < 4; q++) c[j][q] = 0.f;
            }
            for (int v = tid; v < 8192; v += 512) ap[v] = 0ULL;
        } else {
#pragma unroll
            for (int j = 0; j < 4; j++) {
                const int grp = g4 * 4 + j;
                const u32 tv = (u32)t0;
                const u32* tg = &tags[((size_t)((t0 - 1) * 16 + grp) * 4) * 8];
                while (true) {
                    u32 a0 = __hip_atomic_load(&tg[s * 8 + w],   __ATOMIC_RELAXED, __HIP_MEMORY_SCOPE_AGENT);
                    u32 a1 = __hip_atomic_load(&tg[sp1 * 8 + w], __ATOMIC_RELAXED, __HIP_MEMORY_SCOPE_AGENT);
                    u32 a2 = __hip_atomic_load(&tg[sp2 * 8 + w], __ATOMIC_RELAXED, __HIP_MEMORY_SCOPE_AGENT);
                    u32 a3 = __hip_atomic_load(&tg[sp3 * 8 + w], __ATOMIC_RELAXED, __HIP_MEMORY_SCOPE_AGENT);
                    if (a0 == tv && a1 == tv && a2 == tv && a3 == tv) break;
                }
                const u64* hb = &hx[((size_t)((t0 - 1) * 16 + grp) * 4) * 512];
                u64 d0 = __hip_atomic_load(&hb[s * 512 + tid],   __ATOMIC_RELAXED, __HIP_MEMORY_SCOPE_AGENT);
                u64 d1 = __hip_atomic_load(&hb[sp1 * 512 + tid], __ATOMIC_RELAXED, __HIP_MEMORY_SCOPE_AGENT);
                u64 d2 = __hip_atomic_load(&hb[sp2 * 512 + tid], __ATOMIC_RELAXED, __HIP_MEMORY_SCOPE_AGENT);
                u64 d3 = __hip_atomic_load(&hb[sp3 * 512 + tid], __ATOMIC_RELAXED, __HIP_MEMORY_SCOPE_AGENT);
                ap[(size_t)j * 2048 + myrow * 64 + ((s * 16 + mcb) ^ swz)]   = d0;
                ap[(size_t)j * 2048 + myrow * 64 + ((sp1 * 16 + mcb) ^ swz)] = d1;
                ap[(size_t)j * 2048 + myrow * 64 + ((sp2 * 16 + mcb) ^ swz)] = d2;
                ap[(size_t)j * 2048 + myrow * 64 + ((sp3 * 16 + mcb) ^ swz)] = d3;
                ownh[j] = d0;
#pragma unroll
                for (int q = 0; q < 4; q++) c[j][q] = cs[j * 4 + q];
            }
        }
        __syncthreads();

        // prologue xg load: group g4*4+0, tc=0
        const size_t xg_l16 = (size_t)l * 16;
        h8 xcur0 = *(const h8*)&xgp0[((((size_t)(g4 * 4 + 0) * 4 + s) * 8 + w) * 64) * 16 + xg_l16];
        h8 xcur1 = *(const h8*)&xgp0[((((size_t)(g4 * 4 + 0) * 4 + s) * 8 + w) * 64) * 16 + xg_l16 + 8];

        for (int tc = 0; tc < TC; tc++) {
            const int t = t0 + tc;
#pragma unroll
            for (int j = 0; j < 4; j++) {
                const int grp = g4 * 4 + j;
                const int jn = (j + 1) & 3, grpn = g4 * 4 + jn;
                const int src_t = (j == 3) ? t : (t - 1);
                const int tgt_tc = (j == 3) ? (tc + 1) : tc;
                const bool do_xg = (tgt_tc < TC);
                const bool do_gather = do_xg && (src_t >= 0);

                h8 xn0 = xcur0, xn1 = xcur1;
                if (do_xg) {
                    const size_t xb = (size_t)tgt_tc * 524288 +
                                      ((((size_t)grpn * 4 + s) * 8 + w) * 64) * 16 + xg_l16;
                    xn0 = *(const h8*)&xgp0[xb];
                    xn1 = *(const h8*)&xgp0[xb + 8];
                }
                u64 d1 = 0, d2 = 0, d3 = 0;
                if (do_gather) {
                    const u32 tv = (u32)(src_t + 1);
                    const u32* tg = &tags[((size_t)(src_t * 16 + grpn) * 4) * 8];
                    while (true) {
                        u32 a1 = __hip_atomic_load(&tg[sp1 * 8 + w], __ATOMIC_RELAXED, __HIP_MEMORY_SCOPE_AGENT);
                        u32 a2 = __hip_atomic_load(&tg[sp2 * 8 + w], __ATOMIC_RELAXED, __HIP_MEMORY_SCOPE_AGENT);
                        u32 a3 = __hip_atomic_load(&tg[sp3 * 8 + w], __ATOMIC_RELAXED, __HIP_MEMORY_SCOPE_AGENT);
                        if (a1 == tv && a2 == tv && a3 == tv) break;
                    }
                    const u64* hb = &hx[((size_t)(src_t * 16 + grpn) * 4) * 512];
                    d1 = __hip_atomic_load(&hb[sp1 * 512 + tid], __ATOMIC_RELAXED, __HIP_MEMORY_SCOPE_AGENT);
                    d2 = __hip_atomic_load(&hb[sp2 * 512 + tid], __ATOMIC_RELAXED, __HIP_MEMORY_SCOPE_AGENT);
                    d3 = __hip_atomic_load(&hb[sp3 * 512 + tid], __ATOMIC_RELAXED, __HIP_MEMORY_SCOPE_AGENT);
                }

                // gates^T = xg + W_slice @ h^T
                f4 acc[4];
#pragma unroll
                for (int q = 0; q < 4; q++) {
                    acc[0][q] = (float)xcur0[q];
                    acc[1][q] = (float)xcur0[4 + q];
                    acc[2][q] = (float)xcur1[q];
                    acc[3][q] = (float)xcur1[4 + q];
                }
#pragma unroll
                for (int kc = 0; kc < 8; kc++) {
                    int cp = (kc * 8 + (l >> 4) * 2) ^ swz;
                    h8 bv = *(const h8*)&ap[(size_t)j * 2048 + myrow * 64 + cp];
#pragma unroll
                    for (int ga = 0; ga < 4; ga++)
                        acc[ga] = __builtin_amdgcn_mfma_f32_16x16x32_f16(wreg[ga][kc], bv, acc[ga], 0, 0, 0);
                }

                // cell update: acc[ga][q] = gate ga, h-col q4*16+(l>>4)*4+q, row myrow
                float hv[4];
#pragma unroll
                for (int q = 0; q < 4; q++) {
                    float gi = acc[0][q], gf = acc[1][q], gg = acc[2][q], go = acc[3][q];
                    float cn = sigm(gf) * c[j][q] + sigm(gi) * tanhf_(gg);
                    c[j][q] = cn;
                    hv[q] = sigm(go) * tanhf_(cn);
                }
                if (t == 127) {
                    f4 o;
#pragma unroll
                    for (int q = 0; q < 4; q++) o[q] = hv[q];
                    *(f4*)&h_all[(size_t)(grp * 32 + myrow) * 384 + s * 64 + q4 * 16 + (l >> 4) * 4] = o;
                } else {
                    h4 hp;
#pragma unroll
                    for (int q = 0; q < 4; q++) hp[q] = (_Float16)hv[q];
                    u64 hu = *(u64*)&hp;
                    __hip_atomic_store(&hx[((size_t)(t * 16 + grp) * 4 + s) * 512 + tid], hu,
                                       __ATOMIC_RELAXED, __HIP_MEMORY_SCOPE_AGENT);
                    if (l == 0)
                        __hip_atomic_store(&tags[((size_t)(t * 16 + grp) * 4 + s) * 8 + w], (u32)(t + 1),
                                           __ATOMIC_RELEASE, __HIP_MEMORY_SCOPE_AGENT);
                    ownh[j] = hu;
                }
                if (do_gather) {
                    ap[(size_t)jn * 2048 + myrow * 64 + ((sp1 * 16 + mcb) ^ swz)] = d1;
                    ap[(size_t)jn * 2048 + myrow * 64 + ((sp2 * 16 + mcb) ^ swz)] = d2;
                    ap[(size_t)jn * 2048 + myrow * 64 + ((sp3 * 16 + mcb) ^ swz)] = d3;
                    ap[(size_t)jn * 2048 + myrow * 64 + ((s * 16 + mcb) ^ swz)]   = ownh[jn];
                }
                __syncthreads();
                xcur0 = xn0; xcur1 = xn1;
            }
        }
        if (t0 + TC < 128) {
#pragma unroll
            for (int j = 0; j < 4; j++)
#pragma unroll
                for (int q = 0; q < 4; q++) cs[j * 4 + q] = c[j][q];
        }
    } else {
        // ----- LSTM1 / LSTM2 (LDS-resident, unchanged structure) -----
        const int idx12 = hi8 * 4 + (r8 - 4);    // 0..15
        const int m = (idx12 < 8) ? 1 : 2;
        const int lb = idx12 & 7;
        const int r0 = lb * 64;
        const int colb = (m == 1) ? 256 : 320;
        const _Float16* whhp = (m == 1) ? whhp1 : whhp2;
        const _Float16* xgp  = (m == 1) ? xgp1 : xgp2;
        _Float16* whhs = (_Float16*)smem;                 // 32 KB
        _Float16* apkA = (_Float16*)(smem + 32768);       // 8 KB
        _Float16* apkB = (_Float16*)(smem + 40960);       // 8 KB
        const int rh = w >> 2, ht = w & 3;
        float c[8];
        h8 xbuf[4];
        float* cs = csave + 131072 + (((size_t)idx12) * 512 + tid) * 8;
        for (int v = tid; v < 2048; v += 512) ((u32x4*)whhs)[v] = ((const u32x4*)whhp)[v];
        if (t0 == 0) {
#pragma unroll
            for (int i = 0; i < 8; i++) c[i] = 0.f;
            u32x4 z = (u32x4){0u, 0u, 0u, 0u};
            for (int v = tid; v < 512; v += 512) ((u32x4*)apkA)[v] = z;
        } else {
#pragma unroll
            for (int i = 0; i < 8; i++) c[i] = cs[i];
            const u32x4* hsrc = (const u32x4*)(hsave + (size_t)idx12 * 4096);
            for (int v = tid; v < 512; v += 512) ((u32x4*)apkA)[v] = hsrc[v];
        }
        __syncthreads();

        const size_t xbase = ((size_t)lb * 8 + w) * 4 * 512 + (size_t)l * 8;
#pragma unroll
        for (int fp = 0; fp < 4; fp++)
            xbuf[fp] = *(const h8*)&xgp[xbase + (size_t)fp * 512];

        f4 acc[2][4];
        for (int tc = 0; tc < TC; tc++) {
            _Float16* cur = (tc & 1) ? apkB : apkA;
            _Float16* nxt = (tc & 1) ? apkA : apkB;
#pragma unroll
            for (int rr = 0; rr < 2; rr++)
#pragma unroll
            for (int gp = 0; gp < 2; gp++) {
                int fp = rr * 2 + gp;
#pragma unroll
                for (int q = 0; q < 4; q++) {
                    acc[rr][2 * gp][q]     = (float)xbuf[fp][q];
                    acc[rr][2 * gp + 1][q] = (float)xbuf[fp][4 + q];
                }
            }
            if (tc + 1 < TC) {
                size_t nb = xbase + (size_t)(tc + 1) * 8 * 8 * 4 * 512;
#pragma unroll
                for (int fp = 0; fp < 4; fp++)
                    xbuf[fp] = *(const h8*)&xgp[nb + (size_t)fp * 512];
            }
#pragma unroll
            for (int kc = 0; kc < 2; kc++) {
                h8 a0 = *(const h8*)&cur[(((rh * 2 + 0) * 2 + kc) * 64 + l) * 8];
                h8 a1 = *(const h8*)&cur[(((rh * 2 + 1) * 2 + kc) * 64 + l) * 8];
#pragma unroll
                for (int ga = 0; ga < 4; ga++) {
                    int gt = ga * 4 + ht;
                    h8 b = *(const h8*)&whhs[((gt * 2 + kc) * 64 + l) * 8];
                    acc[0][ga] = __builtin_amdgcn_mfma_f32_16x16x32_f16(a0, b, acc[0][ga], 0, 0, 0);
                    acc[1][ga] = __builtin_amdgcn_mfma_f32_16x16x32_f16(a1, b, acc[1][ga], 0, 0, 0);
                }
            }
            const int t = t0 + tc;
#pragma unroll
            for (int rr = 0; rr < 2; rr++)
#pragma unroll
            for (int q = 0; q < 4; q++) {
                int idx = rr * 4 + q;
                float gi = acc[rr][0][q];
                float gf = acc[rr][1][q];
                float gg = acc[rr][2][q];
                float go = acc[rr][3][q];
                float cn = sigm(gf) * c[idx] + sigm(gi) * tanhf_(gg);
                c[idx] = cn;
                float hv = sigm(go) * tanhf_(cn);
                int row = (rh * 2 + rr) * 16 + crow + q;
                int hcol = ht * 16 + ccol;
                if (t == 127) h_all[(size_t)(r0 + row) * 384 + colb + hcol] = hv;
                int kch = ht >> 1;
                int sub = (ht & 1) * 2 + (ccol >> 3);
                nxt[(((row >> 4) * 2 + kch) * 64 + sub * 16 + (row & 15)) * 8 + (ccol & 7)] = (_Float16)hv;
            }
            __syncthreads();
        }
        if (t0 + TC < 128) {
#pragma unroll
            for (int i = 0; i < 8; i++) cs[i] = c[i];
            u32x4* hdst = (u32x4*)(hsave + (size_t)idx12 * 4096);
            const u32x4* src = (const u32x4*)((TC & 1) ? apkB : apkA);
            for (int v = tid; v < 512; v += 512) hdst[v] = src[v];
        }
    }
}

// ---------------------------------------------------------------------------
// MLP head (unchanged — verified)
// ---------------------------------------------------------------------------
__global__ __launch_bounds__(512) void mlp_kernel(const float* __restrict__ h_all,
                                                  const float* __restrict__ w1,
                                                  const float* __restrict__ b1,
                                                  const float* __restrict__ w2,
                                                  const float* __restrict__ b2,
                                                  float* __restrict__ out)
{
    __shared__ float w1s[64 * 385];
    __shared__ float hs[8 * 384];
    int tid = threadIdx.x;
    for (int idx = tid; idx < 64 * 384; idx += 512) {
        int j = idx / 384, k = idx - j * 384;
        w1s[j * 385 + k] = w1[idx];
    }
    int r0 = blockIdx.x * 8;
    for (int idx = tid; idx < 8 * 384; idx += 512) hs[idx] = h_all[(size_t)r0 * 384 + idx];
    __syncthreads();

    int w = tid >> 6, j = tid & 63;
    float accv = b1[j];
    const float* hrow = &hs[w * 384];
    for (int k = 0; k < 384; k++) accv = fmaf(hrow[k], w1s[j * 385 + k], accv);
    float hid = fmaxf(accv, 0.f);
    float v = hid * w2[j];
#pragma unroll
    for (int off = 32; off >= 1; off >>= 1) v += __shfl_xor(v, off, 64);
    if (j == 0) out[r0 + w] = v + b2[0];
}

// ---------------------------------------------------------------------------
extern "C" void kernel_launch(void* const* d_in, const int* in_sizes, int n_in,
                              void* d_out, int out_size, void* d_ws, size_t ws_size,
                              hipStream_t stream)
{
    const float* x0   = (const float*)d_in[0];
    const float* x1   = (const float*)d_in[1];
    const float* x2   = (const float*)d_in[2];
    const float* wih0 = (const float*)d_in[3];
    const float* whh0 = (const float*)d_in[4];
    const float* bih0 = (const float*)d_in[5];
    const float* bhh0 = (const float*)d_in[6];
    const float* wih1 = (const float*)d_in[7];
    const float* whh1 = (const float*)d_in[8];
    const float* bih1 = (const float*)d_in[9];
    const float* bhh1 = (const float*)d_in[10];
    const float* wih2 = (const float*)d_in[11];
    const float* whh2 = (const float*)d_in[12];
    const float* bih2 = (const float*)d_in[13];
    const float* bhh2 = (const float*)d_in[14];
    const float* w1   = (const float*)d_in[15];
    const float* b1   = (const float*)d_in[16];
    const float* w2   = (const float*)d_in[17];
    const float* b2   = (const float*)d_in[18];

    char* ws = (char*)d_ws;
    size_t off = 0;
    auto alloc = [&](size_t bytes) { size_t o = off; off = (off + bytes + 255) & ~255ULL; return o; };
    size_t o_wihp0 = alloc(655360);
    size_t o_whhp0 = alloc(524288);
    size_t o_wihp1 = alloc(49152);
    size_t o_whhp1 = alloc(32768);
    size_t o_wihp2 = alloc(32768);
    size_t o_whhp2 = alloc(32768);
    size_t o_bias  = alloc(6144);
    size_t o_hall  = alloc(786432);
    size_t o_csave = alloc(786432);
    size_t o_hsave = alloc(131072);
    size_t o_hx    = alloc(33554432);   // hx[128][16][4][512] u64 (4KB per slice)
    size_t o_tags  = alloc(262144);     // tags[128][16][4][8] u32
    size_t fixed = off;

    int TC = 128;
    while (TC > 1 && fixed + (size_t)TC * 1572864ULL + 1024 > ws_size) TC >>= 1;
    size_t o_xgp0 = alloc((size_t)TC * 1048576ULL);
    size_t o_xgp1 = alloc((size_t)TC * 262144ULL);
    size_t o_xgp2 = alloc((size_t)TC * 262144ULL);

    _Float16* wihp0 = (_Float16*)(ws + o_wihp0);
    _Float16* whhp0 = (_Float16*)(ws + o_whhp0);
    _Float16* wihp1 = (_Float16*)(ws + o_wihp1);
    _Float16* whhp1 = (_Float16*)(ws + o_whhp1);
    _Float16* wihp2 = (_Float16*)(ws + o_wihp2);
    _Float16* whhp2 = (_Float16*)(ws + o_whhp2);
    float*    biasc = (float*)(ws + o_bias);
    float*    hall  = (float*)(ws + o_hall);
    float*    csave = (float*)(ws + o_csave);
    _Float16* hsave = (_Float16*)(ws + o_hsave);
    u64*      hx    = (u64*)(ws + o_hx);
    u32*      tags  = (u32*)(ws + o_tags);
    _Float16* xgp0  = (_Float16*)(ws + o_xgp0);
    _Float16* xgp1  = (_Float16*)(ws + o_xgp1);
    _Float16* xgp2  = (_Float16*)(ws + o_xgp2);

    hipMemsetAsync(ws + o_tags, 0, 262144, stream);

    pack_all<<<330, 256, 0, stream>>>(wih0, whh0, wih1, whh1, wih2, whh2,
                                      bih0, bhh0, bih1, bhh1, bih2, bhh2,
                                      wihp0, whhp0, wihp1, whhp1, wihp2, whhp2, biasc);

    for (int t0 = 0; t0 < 128; t0 += TC) {
        xg_kernel<<<24 * TC, 512, 0, stream>>>(x0, x1, x2, wihp0, wihp1, wihp2, biasc,
                                               xgp0, xgp1, xgp2, t0, TC);
        rec_kernel<<<32, 512, 0, stream>>>(whhp0, whhp1, whhp2, xgp0, xgp1, xgp2,
                                           hall, csave, hsave, hx, tags, t0, TC);
    }

    mlp_kernel<<<64, 512, 0, stream>>>(hall, w1, b1, w2, b2, (float*)d_out);
}

// Round 9
// 2105.981 us; speedup vs baseline: 1.4249x; 1.0763x over previous
//
#include <hip/hip_runtime.h>

typedef _Float16 h8 __attribute__((ext_vector_type(8)));
typedef _Float16 h4 __attribute__((ext_vector_type(4)));
typedef float f4 __attribute__((ext_vector_type(4)));
typedef unsigned int u32x4 __attribute__((ext_vector_type(4)));
typedef unsigned long long u64;
typedef unsigned int u32;

__device__ __forceinline__ float sigm(float x) { return 1.f / (1.f + __expf(-x)); }
__device__ __forceinline__ float tanhf_(float x) { return 1.f - 2.f / (1.f + __expf(2.f * x)); }

// ---------------------------------------------------------------------------
// pack_all: weights -> f16 fragment layout [gt][kc][lane][8],
// value(gt,kc,lane,i) = W[gt*16 + (lane&15)][kc*32 + ((lane>>4)<<3) + i] (0-pad).
// biasc = b_ih + b_hh (f32).  (unchanged — verified)
// ---------------------------------------------------------------------------
__global__ __launch_bounds__(256) void pack_all(
    const float* __restrict__ wih0, const float* __restrict__ whh0,
    const float* __restrict__ wih1, const float* __restrict__ whh1,
    const float* __restrict__ wih2, const float* __restrict__ whh2,
    const float* __restrict__ bih0, const float* __restrict__ bhh0,
    const float* __restrict__ bih1, const float* __restrict__ bhh1,
    const float* __restrict__ bih2, const float* __restrict__ bhh2,
    _Float16* __restrict__ wihp0, _Float16* __restrict__ whhp0,
    _Float16* __restrict__ wihp1, _Float16* __restrict__ whhp1,
    _Float16* __restrict__ wihp2, _Float16* __restrict__ whhp2,
    float* __restrict__ biasc)
{
    if (blockIdx.x >= 324) {
        int bi = (blockIdx.x - 324) * 256 + threadIdx.x;
        if (bi < 1024)      biasc[bi] = bih0[bi] + bhh0[bi];
        else if (bi < 1280) biasc[bi] = bih1[bi - 1024] + bhh1[bi - 1024];
        else if (bi < 1536) biasc[bi] = bih2[bi - 1280] + bhh2[bi - 1280];
        return;
    }
    int s = blockIdx.x * 256 + threadIdx.x;
    const float* src; _Float16* dst; int KC, D;
    if (s < 40960)      {            dst = wihp0; src = wih0; KC = 10; D = 300; }
    else if (s < 73728) { s -= 40960; dst = whhp0; src = whh0; KC = 8;  D = 256; }
    else if (s < 76800) { s -= 73728; dst = wihp1; src = wih1; KC = 3;  D = 74;  }
    else if (s < 78848) { s -= 76800; dst = whhp1; src = whh1; KC = 2;  D = 64;  }
    else if (s < 80896) { s -= 78848; dst = wihp2; src = wih2; KC = 2;  D = 35;  }
    else                { s -= 80896; dst = whhp2; src = whh2; KC = 2;  D = 64;  }
    int lane = s & 63;
    int kc = (s >> 6) % KC;
    int gt = (s >> 6) / KC;
    int g = gt * 16 + (lane & 15);
    int kb = kc * 32 + ((lane >> 4) << 3);
    h8 v;
#pragma unroll
    for (int i = 0; i < 8; i++) {
        int k = kb + i;
        v[i] = (_Float16)((k < D) ? src[(size_t)g * D + k] : 0.f);
    }
    *(h8*)&dst[(size_t)s * 8] = v;
}

// ---------------------------------------------------------------------------
// xg phase: xg = x @ w_ih^T + bias (f16), pre-packed for the recurrence.
// LSTM0 (NEW): xgp0[tc][grp(8)][s(8)][w2(8)][lane(64)][16],
//   w2 = u*4+bt, offset = gate*4+q holds xg^T[gate-row][batch] for
//   gate-row tile gt = gate*16 + s*2 + u, batch tile bt within 64-row grp.
// LSTM1/2 (unchanged): [tc][bq(8)][w(8)][fp(4)][lane(64)][8]
// ---------------------------------------------------------------------------
template <int M>
__device__ __forceinline__ void xg_block(int tc, int bq, int t0,
    const float* __restrict__ x, const _Float16* __restrict__ wihp,
    const float* __restrict__ bias, _Float16* __restrict__ xgp, _Float16* axf)
{
    constexpr int D   = (M == 0) ? 300 : ((M == 1) ? 74 : 35);
    constexpr int KCX = (M == 0) ? 10 : ((M == 1) ? 3 : 2);
    const int t = t0 + tc;
    const int tid = threadIdx.x, w = tid >> 6, l = tid & 63, ccol = l & 15;
    const int r0 = bq * 64;

    // stage A tile (64 rows x KCX*32 k) as f16 frags in LDS
    for (int sI = tid; sI < 4 * KCX * 64; sI += 512) {
        int rt = sI / (KCX * 64);
        int kc = (sI >> 6) % KCX;
        int ll = sI & 63;
        int row = r0 + rt * 16 + (ll & 15);
        int kb = kc * 32 + ((ll >> 4) << 3);
        const float* bp = x + ((size_t)row * 128 + t) * D + kb;
        h8 v;
#pragma unroll
        for (int i = 0; i < 8; i++) v[i] = (_Float16)((kb + i < D) ? bp[i] : 0.f);
        *(h8*)&axf[sI * 8] = v;
    }
    __syncthreads();

    if (M == 0) {
        // transposed: mfma(A = w_ih frag, B = x frag) -> C[gate-row][batch]
        f4 acc[4][8];
#pragma unroll
        for (int g = 0; g < 8; g++) {
            int gt = (g >> 1) * 16 + 2 * w + (g & 1);
            f4 bv4 = *(const f4*)&bias[gt * 16 + (l >> 4) * 4];
#pragma unroll
            for (int rt = 0; rt < 4; rt++) acc[rt][g] = bv4;
        }
#pragma unroll
        for (int kc = 0; kc < KCX; kc++) {
            h8 a[4];
#pragma unroll
            for (int rt = 0; rt < 4; rt++) a[rt] = *(const h8*)&axf[((rt * KCX + kc) * 64 + l) * 8];
#pragma unroll
            for (int g = 0; g < 8; g++) {
                int gt = (g >> 1) * 16 + 2 * w + (g & 1);
                h8 b = *(const h8*)&wihp[((size_t)(gt * KCX + kc) * 64 + l) * 8];
#pragma unroll
                for (int rt = 0; rt < 4; rt++)
                    acc[rt][g] = __builtin_amdgcn_mfma_f32_16x16x32_f16(b, a[rt], acc[rt][g], 0, 0, 0);
            }
        }
        // store for rec: gt = gate*16 + s*2 + u with s = w, u = g&1, gate = g>>1;
        // grp = bq (64-row group), bt = rt, dest w2 = u*4+bt, lane = l, off = gate*4.
#pragma unroll
        for (int rt = 0; rt < 4; rt++) {
#pragma unroll
            for (int g = 0; g < 8; g++) {
                f4 a = acc[rt][g];
                h4 v;
#pragma unroll
                for (int q = 0; q < 4; q++) v[q] = (_Float16)a[q];
                size_t off = ((((size_t)tc * 8 + bq) * 8 + w) * 8 + ((g & 1) * 4 + rt)) * 64 + l;
                *(h4*)&xgp[off * 16 + (g >> 1) * 4] = v;
            }
        }
    } else {
        const int rh = w >> 2, ht = w & 3;
        f4 acc[2][4];
#pragma unroll
        for (int ga = 0; ga < 4; ga++) {
            int gt = ga * 4 + ht;
            float b = bias[gt * 16 + ccol];
            acc[0][ga] = (f4){b, b, b, b};
            acc[1][ga] = (f4){b, b, b, b};
        }
#pragma unroll
        for (int kc = 0; kc < KCX; kc++) {
            h8 a[2];
#pragma unroll
            for (int rr = 0; rr < 2; rr++)
                a[rr] = *(const h8*)&axf[(((rh * 2 + rr) * KCX + kc) * 64 + l) * 8];
#pragma unroll
            for (int ga = 0; ga < 4; ga++) {
                int gt = ga * 4 + ht;
                h8 b = *(const h8*)&wihp[((size_t)(gt * KCX + kc) * 64 + l) * 8];
#pragma unroll
                for (int rr = 0; rr < 2; rr++)
                    acc[rr][ga] = __builtin_amdgcn_mfma_f32_16x16x32_f16(a[rr], b, acc[rr][ga], 0, 0, 0);
            }
        }
#pragma unroll
        for (int rr = 0; rr < 2; rr++)
#pragma unroll
        for (int gp = 0; gp < 2; gp++) {
            f4 lo = acc[rr][2 * gp], hi = acc[rr][2 * gp + 1];
            h8 v;
#pragma unroll
            for (int q = 0; q < 4; q++) { v[q] = (_Float16)lo[q]; v[4 + q] = (_Float16)hi[q]; }
            int fp = rr * 2 + gp;
            size_t off = ((((size_t)tc * 8 + bq) * 8 + w) * 4 + fp) * 64 + l;
            *(h8*)&xgp[off * 8] = v;
        }
    }
}

__global__ __launch_bounds__(512) __attribute__((amdgpu_waves_per_eu(2, 2)))
void xg_kernel(
    const float* __restrict__ x0, const float* __restrict__ x1, const float* __restrict__ x2,
    const _Float16* __restrict__ wihp0, const _Float16* __restrict__ wihp1,
    const _Float16* __restrict__ wihp2, const float* __restrict__ biasc,
    _Float16* __restrict__ xgp0, _Float16* __restrict__ xgp1, _Float16* __restrict__ xgp2,
    int t0, int TC)
{
    // 96KB pad: 1 block/CU, 2 waves/EU -> 256-VGPR budget (round-8 verified: xg fast)
    __shared__ __align__(16) _Float16 axf[49152];
    int b = blockIdx.x;
    int per = TC * 8;
    if (b < per)            xg_block<0>(b >> 3, b & 7, t0, x0, wihp0, biasc,        xgp0, axf);
    else if (b < 2 * per) { b -= per;     xg_block<1>(b >> 3, b & 7, t0, x1, wihp1, biasc + 1024, xgp1, axf); }
    else                  { b -= 2 * per; xg_block<2>(b >> 3, b & 7, t0, x2, wihp2, biasc + 1280, xgp2, axf); }
}

// ---------------------------------------------------------------------------
// Recurrence. Grid = 64 blocks x 512 threads.
//  r8 = bid&7 (XCD class under round-robin), hi8 = bid>>3.
//  r8<4 : LSTM0, superblock g2 = r8 (2 batch groups of 64 rows,
//         time-multiplexed), col-slice s = hi8 (32 h-cols). The 8 slice-peers
//         of a superblock are ≡ g2 (mod 8) -> same XCD -> L2-local exchange.
//         Weight slice (64KB) in LDS, read per phase (NO register residency —
//         rounds 5-8: regalloc refuses >120 VGPR, spills loop-carried arrays).
//         Per phase j: gather group j^1's h (poll 8 tags + 8 u64, window =
//         one full compute phase), MFMA gates^T for group j from LDS weights,
//         in-register cell update, publish 1 u64/lane + per-wave release tag,
//         one barrier.
//  r8==4: LSTM1 (lb=hi8).  r8==5: LSTM2.  r8>=6: exit.
// ---------------------------------------------------------------------------
__global__ __launch_bounds__(512, 1) void rec_kernel(
    const _Float16* __restrict__ whhp0, const _Float16* __restrict__ whhp1,
    const _Float16* __restrict__ whhp2,
    const _Float16* __restrict__ xgp0, const _Float16* __restrict__ xgp1,
    const _Float16* __restrict__ xgp2,
    float* __restrict__ h_all, float* __restrict__ csave, _Float16* __restrict__ hsave,
    u64* __restrict__ hx, u32* __restrict__ tags,
    int t0, int TC)
{
    // 64KB weights | ap0 34816B | ap1 34816B  = 135168 B (1 block/CU)
    __shared__ __align__(16) char smem[135168];
    const int bid = blockIdx.x;
    const int tid = threadIdx.x, w = tid >> 6, l = tid & 63;
    const int ccol = l & 15, crow = (l >> 4) * 4;
    const int r8 = bid & 7, hi8 = bid >> 3;
    if (r8 >= 6) return;

    if (r8 < 4) {
        // ----- LSTM0 -----
        const int g2 = r8, s = hi8;
        const int u = w >> 2, bt = w & 3;
        const int lid0 = g2 * 8 + s;                 // 0..31
        _Float16* wsl = (_Float16*)smem;             // [lt(8)][kc(8)][lane(64)][8]
        u64* ap0 = (u64*)(smem + 65536);             // [row(64)][pitch 68] u64
        u64* ap1 = (u64*)(smem + 65536 + 34816);

        // weight slice -> LDS: lt = gate*2+u_t  <->  gt = gate*16 + s*2 + u_t
        for (int v = tid; v < 4096; v += 512) {
            int lt = v >> 9, off = v & 511;
            int gt = (lt >> 1) * 16 + s * 2 + (lt & 1);
            ((u32x4*)wsl)[v] = ((const u32x4*)whhp0)[(size_t)gt * 512 + off];
        }

        const int b_rel = bt * 16 + (l & 15);        // batch row within group
        const int lq = l >> 4;                       // 0..3
        const int jc_own = s * 8 + u * 4 + lq;       // own col-chunk (global /4)
        float c[2][4];
        float* cs = csave + ((size_t)lid0 * 512 + tid) * 8;

        if (t0 == 0) {
#pragma unroll
            for (int j = 0; j < 2; j++)
#pragma unroll
                for (int q = 0; q < 4; q++) c[j][q] = 0.f;
            for (int v = tid; v < 2 * 64 * 68; v += 512) ap0[v] = 0ULL;
        } else {
#pragma unroll
            for (int j = 0; j < 2; j++) {
                const int grp = g2 * 2 + j;
                const u32 tv = (u32)t0;
                const u32* tg = &tags[((size_t)(t0 - 1) * 8 + grp) * 64];
                while (true) {
                    u32 ok = 0;
#pragma unroll
                    for (int sp = 0; sp < 8; sp++)
                        ok += (__hip_atomic_load(&tg[sp * 8 + w], __ATOMIC_RELAXED,
                                                 __HIP_MEMORY_SCOPE_AGENT) == tv) ? 1u : 0u;
                    if (ok == 8u) break;
                }
                const u64* hb = &hx[((size_t)(t0 - 1) * 8 + grp) * 4096];
                u64* apj = j ? ap1 : ap0;
#pragma unroll
                for (int sp = 0; sp < 8; sp++) {
                    u64 d = __hip_atomic_load(&hb[sp * 512 + tid], __ATOMIC_RELAXED,
                                              __HIP_MEMORY_SCOPE_AGENT);
                    apj[b_rel * 68 + sp * 8 + u * 4 + lq] = d;
                }
#pragma unroll
                for (int q = 0; q < 4; q++) c[j][q] = cs[j * 4 + q];
            }
        }
        __syncthreads();

        // prologue xg: (tc=0, j=0) group g2*2
        const size_t xg_l16 = (size_t)l * 16;
        {
            // nothing
        }
        size_t xb0 = ((((size_t)0 * 8 + g2 * 2) * 8 + s) * 8 + w) * 1024 + xg_l16;
        h8 xcur0 = *(const h8*)&xgp0[xb0];
        h8 xcur1 = *(const h8*)&xgp0[xb0 + 8];

        for (int tc = 0; tc < TC; tc++) {
            const int t = t0 + tc;
#pragma unroll
            for (int j = 0; j < 2; j++) {
                const int grp = g2 * 2 + j;
                const int jn = j ^ 1, grpn = g2 * 2 + jn;
                const int src_t = (j == 1) ? t : (t - 1);
                const int tgt_tc = (j == 1) ? (tc + 1) : tc;
                const bool do_xg = (tgt_tc < TC);
                const bool do_gather = do_xg && (src_t >= 0);
                u64* apj = j ? ap1 : ap0;
                u64* apn = j ? ap0 : ap1;

                h8 xn0 = xcur0, xn1 = xcur1;
                if (do_xg) {
                    size_t xb = ((((size_t)tgt_tc * 8 + grpn) * 8 + s) * 8 + w) * 1024 + xg_l16;
                    xn0 = *(const h8*)&xgp0[xb];
                    xn1 = *(const h8*)&xgp0[xb + 8];
                }
                u64 d[8];
                if (do_gather) {
                    const u32 tv = (u32)(src_t + 1);
                    const u32* tg = &tags[((size_t)src_t * 8 + grpn) * 64];
                    while (true) {
                        u32 ok = 0;
#pragma unroll
                        for (int sp = 0; sp < 8; sp++)
                            ok += (__hip_atomic_load(&tg[sp * 8 + w], __ATOMIC_RELAXED,
                                                     __HIP_MEMORY_SCOPE_AGENT) == tv) ? 1u : 0u;
                        if (ok == 8u) break;
                    }
                    const u64* hb = &hx[((size_t)src_t * 8 + grpn) * 4096];
#pragma unroll
                    for (int sp = 0; sp < 8; sp++)
                        d[sp] = __hip_atomic_load(&hb[sp * 512 + tid], __ATOMIC_RELAXED,
                                                  __HIP_MEMORY_SCOPE_AGENT);
                }

                // gates^T = xg + W_slice @ h^T   (A = LDS weight frag, B = ap frag)
                f4 acc[4];
#pragma unroll
                for (int q = 0; q < 4; q++) {
                    acc[0][q] = (float)xcur0[q];
                    acc[1][q] = (float)xcur0[4 + q];
                    acc[2][q] = (float)xcur1[q];
                    acc[3][q] = (float)xcur1[4 + q];
                }
#pragma unroll
                for (int kc = 0; kc < 8; kc++) {
                    h8 bv = *(const h8*)&apj[b_rel * 68 + kc * 8 + lq * 2];
#pragma unroll
                    for (int g = 0; g < 4; g++) {
                        h8 wa = *(const h8*)&wsl[(((g * 2 + u) * 8 + kc) * 64 + l) * 8];
                        acc[g] = __builtin_amdgcn_mfma_f32_16x16x32_f16(wa, bv, acc[g], 0, 0, 0);
                    }
                }

                // cell update: lane holds cols j0..j0+3 (j0 = s*32+u*16+lq*4), row b_rel
                float hv[4];
#pragma unroll
                for (int q = 0; q < 4; q++) {
                    float gi = acc[0][q], gf = acc[1][q], gg = acc[2][q], go = acc[3][q];
                    float cn = sigm(gf) * c[j][q] + sigm(gi) * tanhf_(gg);
                    c[j][q] = cn;
                    hv[q] = sigm(go) * tanhf_(cn);
                }
                if (t == 127) {
                    f4 o;
#pragma unroll
                    for (int q = 0; q < 4; q++) o[q] = hv[q];
                    *(f4*)&h_all[(size_t)(grp * 64 + b_rel) * 384 + s * 32 + u * 16 + lq * 4] = o;
                } else {
                    h4 hp;
#pragma unroll
                    for (int q = 0; q < 4; q++) hp[q] = (_Float16)hv[q];
                    u64 hu = *(u64*)&hp;
                    __hip_atomic_store(&hx[(((size_t)t * 8 + grp) * 8 + s) * 512 + tid], hu,
                                       __ATOMIC_RELAXED, __HIP_MEMORY_SCOPE_AGENT);
                    if (l == 0)
                        __hip_atomic_store(&tags[(((size_t)t * 8 + grp) * 8 + s) * 8 + w],
                                           (u32)(t + 1), __ATOMIC_RELEASE, __HIP_MEMORY_SCOPE_AGENT);
                }
                if (do_gather) {
#pragma unroll
                    for (int sp = 0; sp < 8; sp++)
                        apn[b_rel * 68 + sp * 8 + u * 4 + lq] = d[sp];
                }
                __syncthreads();
                xcur0 = xn0; xcur1 = xn1;
            }
        }
        if (t0 + TC < 128) {
#pragma unroll
            for (int j = 0; j < 2; j++)
#pragma unroll
                for (int q = 0; q < 4; q++) cs[j * 4 + q] = c[j][q];
        }
    } else {
        // ----- LSTM1 / LSTM2 (LDS-resident, unchanged structure) -----
        const int m = (r8 == 4) ? 1 : 2;
        const int lb = hi8;
        const int idx12 = (m - 1) * 8 + lb;          // 0..15
        const int r0 = lb * 64;
        const int colb = (m == 1) ? 256 : 320;
        const _Float16* whhp = (m == 1) ? whhp1 : whhp2;
        const _Float16* xgp  = (m == 1) ? xgp1 : xgp2;
        _Float16* whhs = (_Float16*)smem;                 // 32 KB
        _Float16* apkA = (_Float16*)(smem + 32768);       // 8 KB
        _Float16* apkB = (_Float16*)(smem + 40960);       // 8 KB
        const int rh = w >> 2, ht = w & 3;
        float c[8];
        h8 xbuf[4];
        float* cs = csave + 131072 + (((size_t)idx12) * 512 + tid) * 8;
        for (int v = tid; v < 2048; v += 512) ((u32x4*)whhs)[v] = ((const u32x4*)whhp)[v];
        if (t0 == 0) {
#pragma unroll
            for (int i = 0; i < 8; i++) c[i] = 0.f;
            u32x4 z = (u32x4){0u, 0u, 0u, 0u};
            for (int v = tid; v < 512; v += 512) ((u32x4*)apkA)[v] = z;
        } else {
#pragma unroll
            for (int i = 0; i < 8; i++) c[i] = cs[i];
            const u32x4* hsrc = (const u32x4*)(hsave + (size_t)idx12 * 4096);
            for (int v = tid; v < 512; v += 512) ((u32x4*)apkA)[v] = hsrc[v];
        }
        __syncthreads();

        const size_t xbase = ((size_t)lb * 8 + w) * 4 * 512 + (size_t)l * 8;
#pragma unroll
        for (int fp = 0; fp < 4; fp++)
            xbuf[fp] = *(const h8*)&xgp[xbase + (size_t)fp * 512];

        f4 acc[2][4];
        for (int tc = 0; tc < TC; tc++) {
            _Float16* cur = (tc & 1) ? apkB : apkA;
            _Float16* nxt = (tc & 1) ? apkA : apkB;
#pragma unroll
            for (int rr = 0; rr < 2; rr++)
#pragma unroll
            for (int gp = 0; gp < 2; gp++) {
                int fp = rr * 2 + gp;
#pragma unroll
                for (int q = 0; q < 4; q++) {
                    acc[rr][2 * gp][q]     = (float)xbuf[fp][q];
                    acc[rr][2 * gp + 1][q] = (float)xbuf[fp][4 + q];
                }
            }
            if (tc + 1 < TC) {
                size_t nb = xbase + (size_t)(tc + 1) * 8 * 8 * 4 * 512;
#pragma unroll
                for (int fp = 0; fp < 4; fp++)
                    xbuf[fp] = *(const h8*)&xgp[nb + (size_t)fp * 512];
            }
#pragma unroll
            for (int kc = 0; kc < 2; kc++) {
                h8 a0 = *(const h8*)&cur[(((rh * 2 + 0) * 2 + kc) * 64 + l) * 8];
                h8 a1 = *(const h8*)&cur[(((rh * 2 + 1) * 2 + kc) * 64 + l) * 8];
#pragma unroll
                for (int ga = 0; ga < 4; ga++) {
                    int gt = ga * 4 + ht;
                    h8 b = *(const h8*)&whhs[((gt * 2 + kc) * 64 + l) * 8];
                    acc[0][ga] = __builtin_amdgcn_mfma_f32_16x16x32_f16(a0, b, acc[0][ga], 0, 0, 0);
                    acc[1][ga] = __builtin_amdgcn_mfma_f32_16x16x32_f16(a1, b, acc[1][ga], 0, 0, 0);
                }
            }
            const int t = t0 + tc;
#pragma unroll
            for (int rr = 0; rr < 2; rr++)
#pragma unroll
            for (int q = 0; q < 4; q++) {
                int idx = rr * 4 + q;
                float gi = acc[rr][0][q];
                float gf = acc[rr][1][q];
                float gg = acc[rr][2][q];
                float go = acc[rr][3][q];
                float cn = sigm(gf) * c[idx] + sigm(gi) * tanhf_(gg);
                c[idx] = cn;
                float hv = sigm(go) * tanhf_(cn);
                int row = (rh * 2 + rr) * 16 + crow + q;
                int hcol = ht * 16 + ccol;
                if (t == 127) h_all[(size_t)(r0 + row) * 384 + colb + hcol] = hv;
                int kch = ht >> 1;
                int sub = (ht & 1) * 2 + (ccol >> 3);
                nxt[(((row >> 4) * 2 + kch) * 64 + sub * 16 + (row & 15)) * 8 + (ccol & 7)] = (_Float16)hv;
            }
            __syncthreads();
        }
        if (t0 + TC < 128) {
#pragma unroll
            for (int i = 0; i < 8; i++) cs[i] = c[i];
            u32x4* hdst = (u32x4*)(hsave + (size_t)idx12 * 4096);
            const u32x4* src = (const u32x4*)((TC & 1) ? apkB : apkA);
            for (int v = tid; v < 512; v += 512) hdst[v] = src[v];
        }
    }
}

// ---------------------------------------------------------------------------
// MLP head (unchanged — verified)
// ---------------------------------------------------------------------------
__global__ __launch_bounds__(512) void mlp_kernel(const float* __restrict__ h_all,
                                                  const float* __restrict__ w1,
                                                  const float* __restrict__ b1,
                                                  const float* __restrict__ w2,
                                                  const float* __restrict__ b2,
                                                  float* __restrict__ out)
{
    __shared__ float w1s[64 * 385];
    __shared__ float hs[8 * 384];
    int tid = threadIdx.x;
    for (int idx = tid; idx < 64 * 384; idx += 512) {
        int j = idx / 384, k = idx - j * 384;
        w1s[j * 385 + k] = w1[idx];
    }
    int r0 = blockIdx.x * 8;
    for (int idx = tid; idx < 8 * 384; idx += 512) hs[idx] = h_all[(size_t)r0 * 384 + idx];
    __syncthreads();

    int w = tid >> 6, j = tid & 63;
    float accv = b1[j];
    const float* hrow = &hs[w * 384];
    for (int k = 0; k < 384; k++) accv = fmaf(hrow[k], w1s[j * 385 + k], accv);
    float hid = fmaxf(accv, 0.f);
    float v = hid * w2[j];
#pragma unroll
    for (int off = 32; off >= 1; off >>= 1) v += __shfl_xor(v, off, 64);
    if (j == 0) out[r0 + w] = v + b2[0];
}

// ---------------------------------------------------------------------------
extern "C" void kernel_launch(void* const* d_in, const int* in_sizes, int n_in,
                              void* d_out, int out_size, void* d_ws, size_t ws_size,
                              hipStream_t stream)
{
    const float* x0   = (const float*)d_in[0];
    const float* x1   = (const float*)d_in[1];
    const float* x2   = (const float*)d_in[2];
    const float* wih0 = (const float*)d_in[3];
    const float* whh0 = (const float*)d_in[4];
    const float* bih0 = (const float*)d_in[5];
    const float* bhh0 = (const float*)d_in[6];
    const float* wih1 = (const float*)d_in[7];
    const float* whh1 = (const float*)d_in[8];
    const float* bih1 = (const float*)d_in[9];
    const float* bhh1 = (const float*)d_in[10];
    const float* wih2 = (const float*)d_in[11];
    const float* whh2 = (const float*)d_in[12];
    const float* bih2 = (const float*)d_in[13];
    const float* bhh2 = (const float*)d_in[14];
    const float* w1   = (const float*)d_in[15];
    const float* b1   = (const float*)d_in[16];
    const float* w2   = (const float*)d_in[17];
    const float* b2   = (const float*)d_in[18];

    char* ws = (char*)d_ws;
    size_t off = 0;
    auto alloc = [&](size_t bytes) { size_t o = off; off = (off + bytes + 255) & ~255ULL; return o; };
    size_t o_wihp0 = alloc(655360);
    size_t o_whhp0 = alloc(524288);
    size_t o_wihp1 = alloc(49152);
    size_t o_whhp1 = alloc(32768);
    size_t o_wihp2 = alloc(32768);
    size_t o_whhp2 = alloc(32768);
    size_t o_bias  = alloc(6144);
    size_t o_hall  = alloc(786432);
    size_t o_csave = alloc(786432);
    size_t o_hsave = alloc(131072);
    size_t o_hx    = alloc(33554432);   // hx[128][8][8][512] u64
    size_t o_tags  = alloc(262144);     // tags[128][8][8][8] u32
    size_t fixed = off;

    int TC = 128;
    while (TC > 1 && fixed + (size_t)TC * 1572864ULL + 1024 > ws_size) TC >>= 1;
    size_t o_xgp0 = alloc((size_t)TC * 1048576ULL);
    size_t o_xgp1 = alloc((size_t)TC * 262144ULL);
    size_t o_xgp2 = alloc((size_t)TC * 262144ULL);

    _Float16* wihp0 = (_Float16*)(ws + o_wihp0);
    _Float16* whhp0 = (_Float16*)(ws + o_whhp0);
    _Float16* wihp1 = (_Float16*)(ws + o_wihp1);
    _Float16* whhp1 = (_Float16*)(ws + o_whhp1);
    _Float16* wihp2 = (_Float16*)(ws + o_wihp2);
    _Float16* whhp2 = (_Float16*)(ws + o_whhp2);
    float*    biasc = (float*)(ws + o_bias);
    float*    hall  = (float*)(ws + o_hall);
    float*    csave = (float*)(ws + o_csave);
    _Float16* hsave = (_Float16*)(ws + o_hsave);
    u64*      hx    = (u64*)(ws + o_hx);
    u32*      tags  = (u32*)(ws + o_tags);
    _Float16* xgp0  = (_Float16*)(ws + o_xgp0);
    _Float16* xgp1  = (_Float16*)(ws + o_xgp1);
    _Float16* xgp2  = (_Float16*)(ws + o_xgp2);

    hipMemsetAsync(ws + o_tags, 0, 262144, stream);

    pack_all<<<330, 256, 0, stream>>>(wih0, whh0, wih1, whh1, wih2, whh2,
                                      bih0, bhh0, bih1, bhh1, bih2, bhh2,
                                      wihp0, whhp0, wihp1, whhp1, wihp2, whhp2, biasc);

    for (int t0 = 0; t0 < 128; t0 += TC) {
        xg_kernel<<<24 * TC, 512, 0, stream>>>(x0, x1, x2, wihp0, wihp1, wihp2, biasc,
                                               xgp0, xgp1, xgp2, t0, TC);
        rec_kernel<<<64, 512, 0, stream>>>(whhp0, whhp1, whhp2, xgp0, xgp1, xgp2,
                                           hall, csave, hsave, hx, tags, t0, TC);
    }

    mlp_kernel<<<64, 512, 0, stream>>>(hall, w1, b1, w2, b2, (float*)d_out);
}

// Round 10
// 1449.446 us; speedup vs baseline: 2.0703x; 1.4530x over previous
//
#include <hip/hip_runtime.h>

typedef _Float16 h8 __attribute__((ext_vector_type(8)));
typedef _Float16 h4 __attribute__((ext_vector_type(4)));
typedef float f4 __attribute__((ext_vector_type(4)));
typedef unsigned int u32x4 __attribute__((ext_vector_type(4)));
typedef unsigned long long u64;
typedef unsigned int u32;

__device__ __forceinline__ float sigm(float x) { return 1.f / (1.f + __expf(-x)); }
__device__ __forceinline__ float tanhf_(float x) { return 1.f - 2.f / (1.f + __expf(2.f * x)); }

// ---------------------------------------------------------------------------
// pack_all: weights -> f16 fragment layout [gt][kc][lane][8],
// value(gt,kc,lane,i) = W[gt*16 + (lane&15)][kc*32 + ((lane>>4)<<3) + i] (0-pad).
// biasc = b_ih + b_hh (f32).   (round-4 verified, unchanged)
// ---------------------------------------------------------------------------
__global__ __launch_bounds__(256) void pack_all(
    const float* __restrict__ wih0, const float* __restrict__ whh0,
    const float* __restrict__ wih1, const float* __restrict__ whh1,
    const float* __restrict__ wih2, const float* __restrict__ whh2,
    const float* __restrict__ bih0, const float* __restrict__ bhh0,
    const float* __restrict__ bih1, const float* __restrict__ bhh1,
    const float* __restrict__ bih2, const float* __restrict__ bhh2,
    _Float16* __restrict__ wihp0, _Float16* __restrict__ whhp0,
    _Float16* __restrict__ wihp1, _Float16* __restrict__ whhp1,
    _Float16* __restrict__ wihp2, _Float16* __restrict__ whhp2,
    float* __restrict__ biasc)
{
    if (blockIdx.x >= 324) {
        int bi = (blockIdx.x - 324) * 256 + threadIdx.x;
        if (bi < 1024)      biasc[bi] = bih0[bi] + bhh0[bi];
        else if (bi < 1280) biasc[bi] = bih1[bi - 1024] + bhh1[bi - 1024];
        else if (bi < 1536) biasc[bi] = bih2[bi - 1280] + bhh2[bi - 1280];
        return;
    }
    int s = blockIdx.x * 256 + threadIdx.x;
    const float* src; _Float16* dst; int KC, D;
    if (s < 40960)      {            dst = wihp0; src = wih0; KC = 10; D = 300; }
    else if (s < 73728) { s -= 40960; dst = whhp0; src = whh0; KC = 8;  D = 256; }
    else if (s < 76800) { s -= 73728; dst = wihp1; src = wih1; KC = 3;  D = 74;  }
    else if (s < 78848) { s -= 76800; dst = whhp1; src = whh1; KC = 2;  D = 64;  }
    else if (s < 80896) { s -= 78848; dst = wihp2; src = wih2; KC = 2;  D = 35;  }
    else                { s -= 80896; dst = whhp2; src = whh2; KC = 2;  D = 64;  }
    int lane = s & 63;
    int kc = (s >> 6) % KC;
    int gt = (s >> 6) / KC;
    int g = gt * 16 + (lane & 15);
    int kb = kc * 32 + ((lane >> 4) << 3);
    h8 v;
#pragma unroll
    for (int i = 0; i < 8; i++) {
        int k = kb + i;
        v[i] = (_Float16)((k < D) ? src[(size_t)g * D + k] : 0.f);
    }
    *(h8*)&dst[(size_t)s * 8] = v;
}

// ---------------------------------------------------------------------------
// xg phase (round-4 body): xg = x @ w_ih^T + bias (f16), pre-packed.
// LSTM0: xgp0[tc][g(16)][s(4)][w(8)][lane(64)][16]  (rec acc-frag layout)
// LSTM1/2: [tc][bq(8)][w(8)][fp(4)][lane(64)][8]
// NEW vs round 4: amdgpu_waves_per_eu(2,2) + 96KB axf pad (round-8 verified:
// without it the 128-VGPR target spills acc[4][8] and xg costs ~120us).
// ---------------------------------------------------------------------------
template <int M>
__device__ __forceinline__ void xg_block(int tc, int bq, int t0,
    const float* __restrict__ x, const _Float16* __restrict__ wihp,
    const float* __restrict__ bias, _Float16* __restrict__ xgp, _Float16* axf)
{
    constexpr int D   = (M == 0) ? 300 : ((M == 1) ? 74 : 35);
    constexpr int KCX = (M == 0) ? 10 : ((M == 1) ? 3 : 2);
    const int t = t0 + tc;
    const int tid = threadIdx.x, w = tid >> 6, l = tid & 63, ccol = l & 15;
    const int r0 = bq * 64;

    for (int sI = tid; sI < 4 * KCX * 64; sI += 512) {
        int rt = sI / (KCX * 64);
        int kc = (sI >> 6) % KCX;
        int ll = sI & 63;
        int row = r0 + rt * 16 + (ll & 15);
        int kb = kc * 32 + ((ll >> 4) << 3);
        const float* bp = x + ((size_t)row * 128 + t) * D + kb;
        h8 v;
#pragma unroll
        for (int i = 0; i < 8; i++) v[i] = (_Float16)((kb + i < D) ? bp[i] : 0.f);
        *(h8*)&axf[sI * 8] = v;
    }
    __syncthreads();

    if (M == 0) {
        f4 acc[4][8];
#pragma unroll
        for (int g = 0; g < 8; g++) {
            int gt = (g >> 1) * 16 + 2 * w + (g & 1);
            float b = bias[gt * 16 + ccol];
#pragma unroll
            for (int rt = 0; rt < 4; rt++) acc[rt][g] = (f4){b, b, b, b};
        }
#pragma unroll
        for (int kc = 0; kc < KCX; kc++) {
            h8 a[4];
#pragma unroll
            for (int rt = 0; rt < 4; rt++) a[rt] = *(const h8*)&axf[((rt * KCX + kc) * 64 + l) * 8];
#pragma unroll
            for (int g = 0; g < 8; g++) {
                int gt = (g >> 1) * 16 + 2 * w + (g & 1);
                h8 b = *(const h8*)&wihp[((size_t)(gt * KCX + kc) * 64 + l) * 8];
#pragma unroll
                for (int rt = 0; rt < 4; rt++)
                    acc[rt][g] = __builtin_amdgcn_mfma_f32_16x16x32_f16(a[rt], b, acc[rt][g], 0, 0, 0);
            }
        }
        // store in rec-LSTM0 acc-frag layout
#pragma unroll
        for (int rtw = 0; rtw < 4; rtw++) {
            int gr = bq * 2 + (rtw >> 1), rt = rtw & 1;
#pragma unroll
            for (int gi = 0; gi < 8; gi++) {
                int ga = gi >> 1;
                int e = 2 * w + (gi & 1);
                int s2 = e >> 2;
                int w2 = (e & 3) * 2 + rt;
                f4 a = acc[rtw][gi];
                h4 v;
#pragma unroll
                for (int q = 0; q < 4; q++) v[q] = (_Float16)a[q];
                size_t off = (size_t)tc * 524288 +
                             ((((size_t)gr * 4 + s2) * 8 + w2) * 64 + l) * 16 + ga * 4;
                *(h4*)&xgp[off] = v;
            }
        }
    } else {
        const int rh = w >> 2, ht = w & 3;
        f4 acc[2][4];
#pragma unroll
        for (int ga = 0; ga < 4; ga++) {
            int gt = ga * 4 + ht;
            float b = bias[gt * 16 + ccol];
            acc[0][ga] = (f4){b, b, b, b};
            acc[1][ga] = (f4){b, b, b, b};
        }
#pragma unroll
        for (int kc = 0; kc < KCX; kc++) {
            h8 a[2];
#pragma unroll
            for (int rr = 0; rr < 2; rr++)
                a[rr] = *(const h8*)&axf[(((rh * 2 + rr) * KCX + kc) * 64 + l) * 8];
#pragma unroll
            for (int ga = 0; ga < 4; ga++) {
                int gt = ga * 4 + ht;
                h8 b = *(const h8*)&wihp[((size_t)(gt * KCX + kc) * 64 + l) * 8];
#pragma unroll
                for (int rr = 0; rr < 2; rr++)
                    acc[rr][ga] = __builtin_amdgcn_mfma_f32_16x16x32_f16(a[rr], b, acc[rr][ga], 0, 0, 0);
            }
        }
#pragma unroll
        for (int rr = 0; rr < 2; rr++)
#pragma unroll
        for (int gp = 0; gp < 2; gp++) {
            f4 lo = acc[rr][2 * gp], hi = acc[rr][2 * gp + 1];
            h8 v;
#pragma unroll
            for (int q = 0; q < 4; q++) { v[q] = (_Float16)lo[q]; v[4 + q] = (_Float16)hi[q]; }
            int fp = rr * 2 + gp;
            size_t off = ((((size_t)tc * 8 + bq) * 8 + w) * 4 + fp) * 64 + l;
            *(h8*)&xgp[off * 8] = v;
        }
    }
}

__global__ __launch_bounds__(512) __attribute__((amdgpu_waves_per_eu(2, 2)))
void xg_kernel(
    const float* __restrict__ x0, const float* __restrict__ x1, const float* __restrict__ x2,
    const _Float16* __restrict__ wihp0, const _Float16* __restrict__ wihp1,
    const _Float16* __restrict__ wihp2, const float* __restrict__ biasc,
    _Float16* __restrict__ xgp0, _Float16* __restrict__ xgp1, _Float16* __restrict__ xgp2,
    int t0, int TC)
{
    // 96KB pad: 1 block/CU so 2 waves/EU is truthful -> 256-VGPR budget.
    __shared__ __align__(16) _Float16 axf[49152];
    int b = blockIdx.x;
    int per = TC * 8;
    if (b < per)            xg_block<0>(b >> 3, b & 7, t0, x0, wihp0, biasc,        xgp0, axf);
    else if (b < 2 * per) { b -= per;     xg_block<1>(b >> 3, b & 7, t0, x1, wihp1, biasc + 1024, xgp1, axf); }
    else                  { b -= 2 * per; xg_block<2>(b >> 3, b & 7, t0, x2, wihp2, biasc + 1280, xgp2, axf); }
}

// ---------------------------------------------------------------------------
// Recurrence (round-4 structure). Grid = 80 blocks x 512 threads.
//   bid 0-63 : LSTM0, gate-split 4-way. g = bid&15 (32-row batch group),
//              s = bid>>4 (64 h-cols). Peers {g,16+g,32+g,48+g} are congruent
//              mod 8 -> same XCD under round-robin -> L2-local exchange.
//              w_hh slice (128KB) LDS-resident; VGPR ~88 (verified no-spill).
//   NEW vs round 4:
//     * per-wave RELEASE tags replace [B2 drain + tid0 flag]: wave publishes
//       its 64 u64s then lane0 release-tags; reader wave w polls only the 3
//       same-w peer tags. Removes a barrier + block-wide vmcnt drain.
//     * s_sleep(2) backoff in polls: spin-loads congest the L2 queues the
//       producers' stores drain through (round-9 lesson).
//   bid 64-71: LSTM1. 72-79: LSTM2. (LDS-resident, unchanged)
// ---------------------------------------------------------------------------
__global__ __launch_bounds__(512, 1) void rec_kernel(
    const _Float16* __restrict__ whhp0, const _Float16* __restrict__ whhp1,
    const _Float16* __restrict__ whhp2,
    const _Float16* __restrict__ xgp0, const _Float16* __restrict__ xgp1,
    const _Float16* __restrict__ xgp2,
    float* __restrict__ h_all, float* __restrict__ csave, _Float16* __restrict__ hsave,
    u64* __restrict__ hx, u32* __restrict__ tags,
    int t0, int TC)
{
    __shared__ __align__(16) char smem[151552];
    const int bid = blockIdx.x;
    const int tid = threadIdx.x, w = tid >> 6, l = tid & 63;
    const int ccol = l & 15, crow = (l >> 4) * 4;

    if (bid < 64) {
        // ----- LSTM0, slice block -----
        const int g = bid & 15, s = bid >> 4;
        const int r0 = g * 32;
        _Float16* whhs   = (_Float16*)smem;              // [16][8][64][8] = 128KB
        _Float16* apack  = (_Float16*)(smem + 131072);   // [kc8][rt2][64][8] = 16KB
        _Float16* hstage = (_Float16*)(smem + 147456);   // own slice frag image, 4KB
        u64* apack_u64   = (u64*)apack;
        const int hgroup = w >> 1, rt = w & 1;
        const int sp1 = (s + 1) & 3, sp2 = (s + 2) & 3, sp3 = (s + 3) & 3;

        // w_hh slice -> LDS (gt' = ga*4+hgroup  <->  global gt = ga*16 + s*4 + hgroup)
        for (int v = tid; v < 8192; v += 512) {
            int gtl = v >> 9, off = v & 511;
            int gt = (gtl >> 2) * 16 + s * 4 + (gtl & 3);
            ((u32x4*)whhs)[v] = ((const u32x4*)whhp0)[(size_t)gt * 512 + off];
        }
        float c[4];
        float* cs = csave + ((size_t)bid * 512 + tid) * 4;
        if (t0 == 0) {
#pragma unroll
            for (int i = 0; i < 4; i++) c[i] = 0.f;
            u32x4 z = (u32x4){0u, 0u, 0u, 0u};
            for (int v = tid; v < 1024; v += 512) ((u32x4*)apack)[v] = z;
        } else {
#pragma unroll
            for (int i = 0; i < 4; i++) c[i] = cs[i];
            const u32 tv = (u32)t0;
            const u32* tg = &tags[((size_t)(t0 - 1) * 16 + g) * 32];
            while (true) {
                u32 a0 = __hip_atomic_load(&tg[s * 8 + w],   __ATOMIC_RELAXED, __HIP_MEMORY_SCOPE_AGENT);
                u32 a1 = __hip_atomic_load(&tg[sp1 * 8 + w], __ATOMIC_RELAXED, __HIP_MEMORY_SCOPE_AGENT);
                u32 a2 = __hip_atomic_load(&tg[sp2 * 8 + w], __ATOMIC_RELAXED, __HIP_MEMORY_SCOPE_AGENT);
                u32 a3 = __hip_atomic_load(&tg[sp3 * 8 + w], __ATOMIC_RELAXED, __HIP_MEMORY_SCOPE_AGENT);
                if (a0 == tv && a1 == tv && a2 == tv && a3 == tv) break;
                __builtin_amdgcn_s_sleep(2);
            }
            const u64* hb = &hx[((size_t)(t0 - 1) * 16 + g) * 2048];
            u64 d0 = __hip_atomic_load(&hb[s * 512 + tid],   __ATOMIC_RELAXED, __HIP_MEMORY_SCOPE_AGENT);
            u64 d1 = __hip_atomic_load(&hb[sp1 * 512 + tid], __ATOMIC_RELAXED, __HIP_MEMORY_SCOPE_AGENT);
            u64 d2 = __hip_atomic_load(&hb[sp2 * 512 + tid], __ATOMIC_RELAXED, __HIP_MEMORY_SCOPE_AGENT);
            u64 d3 = __hip_atomic_load(&hb[sp3 * 512 + tid], __ATOMIC_RELAXED, __HIP_MEMORY_SCOPE_AGENT);
            apack_u64[s * 512 + tid]   = d0;
            apack_u64[sp1 * 512 + tid] = d1;
            apack_u64[sp2 * 512 + tid] = d2;
            apack_u64[sp3 * 512 + tid] = d3;
        }
        __syncthreads();

        const _Float16* xgb = xgp0 + ((((size_t)g * 4 + s) * 8 + w) * 64 + l) * 16;
        h8 xcur0 = *(const h8*)&xgb[0];
        h8 xcur1 = *(const h8*)&xgb[8];

        f4 acc[4];
        for (int tc = 0; tc < TC; tc++) {
            const int t = t0 + tc;
            // acc init from xg (bias folded)
#pragma unroll
            for (int q = 0; q < 4; q++) {
                acc[0][q] = (float)xcur0[q];
                acc[1][q] = (float)xcur0[4 + q];
                acc[2][q] = (float)xcur1[q];
                acc[3][q] = (float)xcur1[4 + q];
            }
            // prefetch next xg (covered by MFMA + update)
            h8 xn0 = xcur0, xn1 = xcur1;
            if (tc + 1 < TC) {
                xn0 = *(const h8*)&xgb[(size_t)(tc + 1) * 524288];
                xn1 = *(const h8*)&xgb[(size_t)(tc + 1) * 524288 + 8];
            }
            // gates += h @ w_hh_slice^T
#pragma unroll
            for (int kc = 0; kc < 8; kc++) {
                h8 a = *(const h8*)&apack[((kc * 2 + rt) * 64 + l) * 8];
#pragma unroll
                for (int ga = 0; ga < 4; ga++) {
                    h8 b = *(const h8*)&whhs[(((ga * 4 + hgroup) * 8 + kc) * 64 + l) * 8];
                    acc[ga] = __builtin_amdgcn_mfma_f32_16x16x32_f16(a, b, acc[ga], 0, 0, 0);
                }
            }
            // cell update (all 4 gates in-register)
#pragma unroll
            for (int q = 0; q < 4; q++) {
                float gi = acc[0][q], gf = acc[1][q], gg = acc[2][q], go = acc[3][q];
                float cn = sigm(gf) * c[q] + sigm(gi) * tanhf_(gg);
                c[q] = cn;
                float hv = sigm(go) * tanhf_(cn);
                int row = rt * 16 + crow + q;
                int hcol = hgroup * 16 + ccol;
                if (t == 127) {
                    h_all[(size_t)(r0 + row) * 384 + s * 64 + hcol] = hv;
                } else {
                    int lane2 = (((hcol & 31) >> 3) << 4) | (row & 15);
                    hstage[(((hcol >> 5) * 2 + rt) * 64 + lane2) * 8 + (l & 7)] = (_Float16)hv;
                }
            }
            xcur0 = xn0; xcur1 = xn1;
            __syncthreads();   // B1: hstage complete; all apack MFMA reads done
            if (t < 127) {
                // per-wave publish + RELEASE tag (orders this wave's 64 stores)
                u64 hval = ((u64*)hstage)[tid];
                __hip_atomic_store(&hx[(((size_t)t * 16 + g) * 4 + s) * 512 + tid], hval,
                                   __ATOMIC_RELAXED, __HIP_MEMORY_SCOPE_AGENT);
                apack_u64[s * 512 + tid] = hval;
                if (l == 0)
                    __hip_atomic_store(&tags[(((size_t)t * 16 + g) * 4 + s) * 8 + w], (u32)(t + 1),
                                       __ATOMIC_RELEASE, __HIP_MEMORY_SCOPE_AGENT);
                // per-wave poll of 3 same-w peer tags, with sleep backoff
                const u32 tv = (u32)(t + 1);
                const u32* tg = &tags[((size_t)t * 16 + g) * 32];
                while (true) {
                    u32 a1 = __hip_atomic_load(&tg[sp1 * 8 + w], __ATOMIC_RELAXED, __HIP_MEMORY_SCOPE_AGENT);
                    u32 a2 = __hip_atomic_load(&tg[sp2 * 8 + w], __ATOMIC_RELAXED, __HIP_MEMORY_SCOPE_AGENT);
                    u32 a3 = __hip_atomic_load(&tg[sp3 * 8 + w], __ATOMIC_RELAXED, __HIP_MEMORY_SCOPE_AGENT);
                    if (a1 == tv && a2 == tv && a3 == tv) break;
                    __builtin_amdgcn_s_sleep(2);
                }
                // gather 3 peer slices (12KB) -> apack
                const u64* hxs = &hx[(((size_t)t * 16 + g) * 4) * 512];
                u64 v1 = __hip_atomic_load(&hxs[sp1 * 512 + tid], __ATOMIC_RELAXED, __HIP_MEMORY_SCOPE_AGENT);
                u64 v2 = __hip_atomic_load(&hxs[sp2 * 512 + tid], __ATOMIC_RELAXED, __HIP_MEMORY_SCOPE_AGENT);
                u64 v3 = __hip_atomic_load(&hxs[sp3 * 512 + tid], __ATOMIC_RELAXED, __HIP_MEMORY_SCOPE_AGENT);
                apack_u64[sp1 * 512 + tid] = v1;
                apack_u64[sp2 * 512 + tid] = v2;
                apack_u64[sp3 * 512 + tid] = v3;
                __syncthreads();   // B3: apack = full h(t) ready
            }
        }
        if (t0 + TC < 128) {
#pragma unroll
            for (int i = 0; i < 4; i++) cs[i] = c[i];
        }
    } else {
        // ----- LSTM1 / LSTM2 (LDS-resident, unchanged) -----
        const int m = (bid < 72) ? 1 : 2;
        const int lb = (bid - 64) & 7;
        const int r0 = lb * 64;
        const int colb = (m == 1) ? 256 : 320;
        const _Float16* whhp = (m == 1) ? whhp1 : whhp2;
        const _Float16* xgp  = (m == 1) ? xgp1 : xgp2;
        _Float16* whhs = (_Float16*)smem;                 // 32 KB
        _Float16* apkA = (_Float16*)(smem + 32768);       // 8 KB
        _Float16* apkB = (_Float16*)(smem + 40960);       // 8 KB
        const int rh = w >> 2, ht = w & 3;
        float c[8];
        h8 xbuf[4];
        float* cs = csave + 131072 + (((size_t)(bid - 64)) * 512 + tid) * 8;
        for (int v = tid; v < 2048; v += 512) ((u32x4*)whhs)[v] = ((const u32x4*)whhp)[v];
        if (t0 == 0) {
#pragma unroll
            for (int i = 0; i < 8; i++) c[i] = 0.f;
            u32x4 z = (u32x4){0u, 0u, 0u, 0u};
            for (int v = tid; v < 512; v += 512) ((u32x4*)apkA)[v] = z;
        } else {
#pragma unroll
            for (int i = 0; i < 8; i++) c[i] = cs[i];
            const u32x4* hsrc = (const u32x4*)(hsave + (size_t)(bid - 64) * 4096);
            for (int v = tid; v < 512; v += 512) ((u32x4*)apkA)[v] = hsrc[v];
        }
        __syncthreads();

        const size_t xbase = ((size_t)lb * 8 + w) * 4 * 512 + (size_t)l * 8;
#pragma unroll
        for (int fp = 0; fp < 4; fp++)
            xbuf[fp] = *(const h8*)&xgp[xbase + (size_t)fp * 512];

        f4 acc[2][4];
        for (int tc = 0; tc < TC; tc++) {
            _Float16* cur = (tc & 1) ? apkB : apkA;
            _Float16* nxt = (tc & 1) ? apkA : apkB;
#pragma unroll
            for (int rr = 0; rr < 2; rr++)
#pragma unroll
            for (int gp = 0; gp < 2; gp++) {
                int fp = rr * 2 + gp;
#pragma unroll
                for (int q = 0; q < 4; q++) {
                    acc[rr][2 * gp][q]     = (float)xbuf[fp][q];
                    acc[rr][2 * gp + 1][q] = (float)xbuf[fp][4 + q];
                }
            }
            if (tc + 1 < TC) {
                size_t nb = xbase + (size_t)(tc + 1) * 8 * 8 * 4 * 512;
#pragma unroll
                for (int fp = 0; fp < 4; fp++)
                    xbuf[fp] = *(const h8*)&xgp[nb + (size_t)fp * 512];
            }
#pragma unroll
            for (int kc = 0; kc < 2; kc++) {
                h8 a0 = *(const h8*)&cur[(((rh * 2 + 0) * 2 + kc) * 64 + l) * 8];
                h8 a1 = *(const h8*)&cur[(((rh * 2 + 1) * 2 + kc) * 64 + l) * 8];
#pragma unroll
                for (int ga = 0; ga < 4; ga++) {
                    int gt = ga * 4 + ht;
                    h8 b = *(const h8*)&whhs[((gt * 2 + kc) * 64 + l) * 8];
                    acc[0][ga] = __builtin_amdgcn_mfma_f32_16x16x32_f16(a0, b, acc[0][ga], 0, 0, 0);
                    acc[1][ga] = __builtin_amdgcn_mfma_f32_16x16x32_f16(a1, b, acc[1][ga], 0, 0, 0);
                }
            }
            const int t = t0 + tc;
#pragma unroll
            for (int rr = 0; rr < 2; rr++)
#pragma unroll
            for (int q = 0; q < 4; q++) {
                int idx = rr * 4 + q;
                float gi = acc[rr][0][q];
                float gf = acc[rr][1][q];
                float gg = acc[rr][2][q];
                float go = acc[rr][3][q];
                float cn = sigm(gf) * c[idx] + sigm(gi) * tanhf_(gg);
                c[idx] = cn;
                float hv = sigm(go) * tanhf_(cn);
                int row = (rh * 2 + rr) * 16 + crow + q;
                int hcol = ht * 16 + ccol;
                if (t == 127) h_all[(size_t)(r0 + row) * 384 + colb + hcol] = hv;
                int kch = ht >> 1;
                int sub = (ht & 1) * 2 + (ccol >> 3);
                nxt[(((row >> 4) * 2 + kch) * 64 + sub * 16 + (row & 15)) * 8 + (ccol & 7)] = (_Float16)hv;
            }
            __syncthreads();
        }
        if (t0 + TC < 128) {
#pragma unroll
            for (int i = 0; i < 8; i++) cs[i] = c[i];
            u32x4* hdst = (u32x4*)(hsave + (size_t)(bid - 64) * 4096);
            const u32x4* src = (const u32x4*)((TC & 1) ? apkB : apkA);
            for (int v = tid; v < 512; v += 512) hdst[v] = src[v];
        }
    }
}

// ---------------------------------------------------------------------------
// MLP head (unchanged — verified)
// ---------------------------------------------------------------------------
__global__ __launch_bounds__(512) void mlp_kernel(const float* __restrict__ h_all,
                                                  const float* __restrict__ w1,
                                                  const float* __restrict__ b1,
                                                  const float* __restrict__ w2,
                                                  const float* __restrict__ b2,
                                                  float* __restrict__ out)
{
    __shared__ float w1s[64 * 385];
    __shared__ float hs[8 * 384];
    int tid = threadIdx.x;
    for (int idx = tid; idx < 64 * 384; idx += 512) {
        int j = idx / 384, k = idx - j * 384;
        w1s[j * 385 + k] = w1[idx];
    }
    int r0 = blockIdx.x * 8;
    for (int idx = tid; idx < 8 * 384; idx += 512) hs[idx] = h_all[(size_t)r0 * 384 + idx];
    __syncthreads();

    int w = tid >> 6, j = tid & 63;
    float accv = b1[j];
    const float* hrow = &hs[w * 384];
    for (int k = 0; k < 384; k++) accv = fmaf(hrow[k], w1s[j * 385 + k], accv);
    float hid = fmaxf(accv, 0.f);
    float v = hid * w2[j];
#pragma unroll
    for (int off = 32; off >= 1; off >>= 1) v += __shfl_xor(v, off, 64);
    if (j == 0) out[r0 + w] = v + b2[0];
}

// ---------------------------------------------------------------------------
extern "C" void kernel_launch(void* const* d_in, const int* in_sizes, int n_in,
                              void* d_out, int out_size, void* d_ws, size_t ws_size,
                              hipStream_t stream)
{
    const float* x0   = (const float*)d_in[0];
    const float* x1   = (const float*)d_in[1];
    const float* x2   = (const float*)d_in[2];
    const float* wih0 = (const float*)d_in[3];
    const float* whh0 = (const float*)d_in[4];
    const float* bih0 = (const float*)d_in[5];
    const float* bhh0 = (const float*)d_in[6];
    const float* wih1 = (const float*)d_in[7];
    const float* whh1 = (const float*)d_in[8];
    const float* bih1 = (const float*)d_in[9];
    const float* bhh1 = (const float*)d_in[10];
    const float* wih2 = (const float*)d_in[11];
    const float* whh2 = (const float*)d_in[12];
    const float* bih2 = (const float*)d_in[13];
    const float* bhh2 = (const float*)d_in[14];
    const float* w1   = (const float*)d_in[15];
    const float* b1   = (const float*)d_in[16];
    const float* w2   = (const float*)d_in[17];
    const float* b2   = (const float*)d_in[18];

    char* ws = (char*)d_ws;
    size_t off = 0;
    auto alloc = [&](size_t bytes) { size_t o = off; off = (off + bytes + 255) & ~255ULL; return o; };
    size_t o_wihp0 = alloc(655360);
    size_t o_whhp0 = alloc(524288);
    size_t o_wihp1 = alloc(49152);
    size_t o_whhp1 = alloc(32768);
    size_t o_wihp2 = alloc(32768);
    size_t o_whhp2 = alloc(32768);
    size_t o_bias  = alloc(6144);
    size_t o_hall  = alloc(786432);
    size_t o_csave = alloc(786432);
    size_t o_hsave = alloc(131072);
    size_t o_hx    = alloc(33554432);   // hx[128][16][4][512] u64 (4KB per slice)
    size_t o_tags  = alloc(262144);     // tags[128][16][4][8] u32
    size_t fixed = off;

    int TC = 128;
    while (TC > 1 && fixed + (size_t)TC * 1572864ULL + 1024 > ws_size) TC >>= 1;
    size_t o_xgp0 = alloc((size_t)TC * 1048576ULL);
    size_t o_xgp1 = alloc((size_t)TC * 262144ULL);
    size_t o_xgp2 = alloc((size_t)TC * 262144ULL);

    _Float16* wihp0 = (_Float16*)(ws + o_wihp0);
    _Float16* whhp0 = (_Float16*)(ws + o_whhp0);
    _Float16* wihp1 = (_Float16*)(ws + o_wihp1);
    _Float16* whhp1 = (_Float16*)(ws + o_whhp1);
    _Float16* wihp2 = (_Float16*)(ws + o_wihp2);
    _Float16* whhp2 = (_Float16*)(ws + o_whhp2);
    float*    biasc = (float*)(ws + o_bias);
    float*    hall  = (float*)(ws + o_hall);
    float*    csave = (float*)(ws + o_csave);
    _Float16* hsave = (_Float16*)(ws + o_hsave);
    u64*      hx    = (u64*)(ws + o_hx);
    u32*      tags  = (u32*)(ws + o_tags);
    _Float16* xgp0  = (_Float16*)(ws + o_xgp0);
    _Float16* xgp1  = (_Float16*)(ws + o_xgp1);
    _Float16* xgp2  = (_Float16*)(ws + o_xgp2);

    hipMemsetAsync(ws + o_tags, 0, 262144, stream);

    pack_all<<<330, 256, 0, stream>>>(wih0, whh0, wih1, whh1, wih2, whh2,
                                      bih0, bhh0, bih1, bhh1, bih2, bhh2,
                                      wihp0, whhp0, wihp1, whhp1, wihp2, whhp2, biasc);

    for (int t0 = 0; t0 < 128; t0 += TC) {
        xg_kernel<<<24 * TC, 512, 0, stream>>>(x0, x1, x2, wihp0, wihp1, wihp2, biasc,
                                               xgp0, xgp1, xgp2, t0, TC);
        rec_kernel<<<80, 512, 0, stream>>>(whhp0, whhp1, whhp2, xgp0, xgp1, xgp2,
                                           hall, csave, hsave, hx, tags, t0, TC);
    }

    mlp_kernel<<<64, 512, 0, stream>>>(hall, w1, b1, w2, b2, (float*)d_out);
}

// Round 11
// 603.701 us; speedup vs baseline: 4.9706x; 2.4009x over previous
//
#include <hip/hip_runtime.h>

typedef _Float16 h8 __attribute__((ext_vector_type(8)));
typedef _Float16 h4 __attribute__((ext_vector_type(4)));
typedef float f4 __attribute__((ext_vector_type(4)));
typedef unsigned int u32x4 __attribute__((ext_vector_type(4)));
typedef unsigned long long u64;
typedef unsigned int u32;

__device__ __forceinline__ float sigm(float x) { return 1.f / (1.f + __expf(-x)); }
__device__ __forceinline__ float tanhf_(float x) { return 1.f - 2.f / (1.f + __expf(2.f * x)); }

#define SENT 0xFFFFFFFFFFFFFFFFULL

// ---------------------------------------------------------------------------
// pack_all: weights -> f16 fragment layout [gt][kc][lane][8],
// value(gt,kc,lane,i) = W[gt*16 + (lane&15)][kc*32 + ((lane>>4)<<3) + i] (0-pad).
// biasc = b_ih + b_hh (f32).   (round-4 verified, unchanged)
// ---------------------------------------------------------------------------
__global__ __launch_bounds__(256) void pack_all(
    const float* __restrict__ wih0, const float* __restrict__ whh0,
    const float* __restrict__ wih1, const float* __restrict__ whh1,
    const float* __restrict__ wih2, const float* __restrict__ whh2,
    const float* __restrict__ bih0, const float* __restrict__ bhh0,
    const float* __restrict__ bih1, const float* __restrict__ bhh1,
    const float* __restrict__ bih2, const float* __restrict__ bhh2,
    _Float16* __restrict__ wihp0, _Float16* __restrict__ whhp0,
    _Float16* __restrict__ wihp1, _Float16* __restrict__ whhp1,
    _Float16* __restrict__ wihp2, _Float16* __restrict__ whhp2,
    float* __restrict__ biasc)
{
    if (blockIdx.x >= 324) {
        int bi = (blockIdx.x - 324) * 256 + threadIdx.x;
        if (bi < 1024)      biasc[bi] = bih0[bi] + bhh0[bi];
        else if (bi < 1280) biasc[bi] = bih1[bi - 1024] + bhh1[bi - 1024];
        else if (bi < 1536) biasc[bi] = bih2[bi - 1280] + bhh2[bi - 1280];
        return;
    }
    int s = blockIdx.x * 256 + threadIdx.x;
    const float* src; _Float16* dst; int KC, D;
    if (s < 40960)      {            dst = wihp0; src = wih0; KC = 10; D = 300; }
    else if (s < 73728) { s -= 40960; dst = whhp0; src = whh0; KC = 8;  D = 256; }
    else if (s < 76800) { s -= 73728; dst = wihp1; src = wih1; KC = 3;  D = 74;  }
    else if (s < 78848) { s -= 76800; dst = whhp1; src = whh1; KC = 2;  D = 64;  }
    else if (s < 80896) { s -= 78848; dst = wihp2; src = wih2; KC = 2;  D = 35;  }
    else                { s -= 80896; dst = whhp2; src = whh2; KC = 2;  D = 64;  }
    int lane = s & 63;
    int kc = (s >> 6) % KC;
    int gt = (s >> 6) / KC;
    int g = gt * 16 + (lane & 15);
    int kb = kc * 32 + ((lane >> 4) << 3);
    h8 v;
#pragma unroll
    for (int i = 0; i < 8; i++) {
        int k = kb + i;
        v[i] = (_Float16)((k < D) ? src[(size_t)g * D + k] : 0.f);
    }
    *(h8*)&dst[(size_t)s * 8] = v;
}

// ---------------------------------------------------------------------------
// xg phase (round-4 body): xg = x @ w_ih^T + bias (f16), pre-packed.
// LSTM0: xgp0[tc][g(16)][s(4)][w(8)][lane(64)][16]  (rec acc-frag layout)
// LSTM1/2: [tc][bq(8)][w(8)][fp(4)][lane(64)][8]
// amdgpu_waves_per_eu(2,2) + 96KB pad: 256-VGPR budget (else acc spills).
// ---------------------------------------------------------------------------
template <int M>
__device__ __forceinline__ void xg_block(int tc, int bq, int t0,
    const float* __restrict__ x, const _Float16* __restrict__ wihp,
    const float* __restrict__ bias, _Float16* __restrict__ xgp, _Float16* axf)
{
    constexpr int D   = (M == 0) ? 300 : ((M == 1) ? 74 : 35);
    constexpr int KCX = (M == 0) ? 10 : ((M == 1) ? 3 : 2);
    const int t = t0 + tc;
    const int tid = threadIdx.x, w = tid >> 6, l = tid & 63, ccol = l & 15;
    const int r0 = bq * 64;

    for (int sI = tid; sI < 4 * KCX * 64; sI += 512) {
        int rt = sI / (KCX * 64);
        int kc = (sI >> 6) % KCX;
        int ll = sI & 63;
        int row = r0 + rt * 16 + (ll & 15);
        int kb = kc * 32 + ((ll >> 4) << 3);
        const float* bp = x + ((size_t)row * 128 + t) * D + kb;
        h8 v;
#pragma unroll
        for (int i = 0; i < 8; i++) v[i] = (_Float16)((kb + i < D) ? bp[i] : 0.f);
        *(h8*)&axf[sI * 8] = v;
    }
    __syncthreads();

    if (M == 0) {
        f4 acc[4][8];
#pragma unroll
        for (int g = 0; g < 8; g++) {
            int gt = (g >> 1) * 16 + 2 * w + (g & 1);
            float b = bias[gt * 16 + ccol];
#pragma unroll
            for (int rt = 0; rt < 4; rt++) acc[rt][g] = (f4){b, b, b, b};
        }
#pragma unroll
        for (int kc = 0; kc < KCX; kc++) {
            h8 a[4];
#pragma unroll
            for (int rt = 0; rt < 4; rt++) a[rt] = *(const h8*)&axf[((rt * KCX + kc) * 64 + l) * 8];
#pragma unroll
            for (int g = 0; g < 8; g++) {
                int gt = (g >> 1) * 16 + 2 * w + (g & 1);
                h8 b = *(const h8*)&wihp[((size_t)(gt * KCX + kc) * 64 + l) * 8];
#pragma unroll
                for (int rt = 0; rt < 4; rt++)
                    acc[rt][g] = __builtin_amdgcn_mfma_f32_16x16x32_f16(a[rt], b, acc[rt][g], 0, 0, 0);
            }
        }
        // store in rec-LSTM0 acc-frag layout
#pragma unroll
        for (int rtw = 0; rtw < 4; rtw++) {
            int gr = bq * 2 + (rtw >> 1), rt = rtw & 1;
#pragma unroll
            for (int gi = 0; gi < 8; gi++) {
                int ga = gi >> 1;
                int e = 2 * w + (gi & 1);
                int s2 = e >> 2;
                int w2 = (e & 3) * 2 + rt;
                f4 a = acc[rtw][gi];
                h4 v;
#pragma unroll
                for (int q = 0; q < 4; q++) v[q] = (_Float16)a[q];
                size_t off = (size_t)tc * 524288 +
                             ((((size_t)gr * 4 + s2) * 8 + w2) * 64 + l) * 16 + ga * 4;
                *(h4*)&xgp[off] = v;
            }
        }
    } else {
        const int rh = w >> 2, ht = w & 3;
        f4 acc[2][4];
#pragma unroll
        for (int ga = 0; ga < 4; ga++) {
            int gt = ga * 4 + ht;
            float b = bias[gt * 16 + ccol];
            acc[0][ga] = (f4){b, b, b, b};
            acc[1][ga] = (f4){b, b, b, b};
        }
#pragma unroll
        for (int kc = 0; kc < KCX; kc++) {
            h8 a[2];
#pragma unroll
            for (int rr = 0; rr < 2; rr++)
                a[rr] = *(const h8*)&axf[(((rh * 2 + rr) * KCX + kc) * 64 + l) * 8];
#pragma unroll
            for (int ga = 0; ga < 4; ga++) {
                int gt = ga * 4 + ht;
                h8 b = *(const h8*)&wihp[((size_t)(gt * KCX + kc) * 64 + l) * 8];
#pragma unroll
                for (int rr = 0; rr < 2; rr++)
                    acc[rr][ga] = __builtin_amdgcn_mfma_f32_16x16x32_f16(a[rr], b, acc[rr][ga], 0, 0, 0);
            }
        }
#pragma unroll
        for (int rr = 0; rr < 2; rr++)
#pragma unroll
        for (int gp = 0; gp < 2; gp++) {
            f4 lo = acc[rr][2 * gp], hi = acc[rr][2 * gp + 1];
            h8 v;
#pragma unroll
            for (int q = 0; q < 4; q++) { v[q] = (_Float16)lo[q]; v[4 + q] = (_Float16)hi[q]; }
            int fp = rr * 2 + gp;
            size_t off = ((((size_t)tc * 8 + bq) * 8 + w) * 4 + fp) * 64 + l;
            *(h8*)&xgp[off * 8] = v;
        }
    }
}

__global__ __launch_bounds__(512) __attribute__((amdgpu_waves_per_eu(2, 2)))
void xg_kernel(
    const float* __restrict__ x0, const float* __restrict__ x1, const float* __restrict__ x2,
    const _Float16* __restrict__ wihp0, const _Float16* __restrict__ wihp1,
    const _Float16* __restrict__ wihp2, const float* __restrict__ biasc,
    _Float16* __restrict__ xgp0, _Float16* __restrict__ xgp1, _Float16* __restrict__ xgp2,
    int t0, int TC)
{
    __shared__ __align__(16) _Float16 axf[49152];   // 96KB pad: 1 block/CU
    int b = blockIdx.x;
    int per = TC * 8;
    if (b < per)            xg_block<0>(b >> 3, b & 7, t0, x0, wihp0, biasc,        xgp0, axf);
    else if (b < 2 * per) { b -= per;     xg_block<1>(b >> 3, b & 7, t0, x1, wihp1, biasc + 1024, xgp1, axf); }
    else                  { b -= 2 * per; xg_block<2>(b >> 3, b & 7, t0, x2, wihp2, biasc + 1280, xgp2, axf); }
}

// ---------------------------------------------------------------------------
// Recurrence (round-4 structure + SENTINEL exchange). Grid = 80 x 512.
//   bid 0-63 : LSTM0, gate-split 4-way. g = bid&15 (32-row batch group),
//              s = bid>>4 (64 h-cols). Peers {g,16+g,32+g,48+g} ≡ g mod 8 ->
//              same XCD -> L2-local exchange. w_hh slice 128KB in LDS.
//   SENTINEL exchange (round-11): hx pre-memset to 0xFF (legit h4 values are
//   finite sigmoid*tanh products -> never the f16 NaN pattern 0xFFFF).
//   Producer: relaxed atomic u64 store. Consumer: relaxed atomic u64 loads,
//   retry while == SENT. Removes vs round 4: B2 block-wide vmcnt drain,
//   tid0 flag store, and the flag->data second visibility round trip.
//   NO release/acquire (agent-scope release = L2 writeback on this chip:
//   round-10 3x regression), NO s_sleep.
//   bid 64-71: LSTM1. 72-79: LSTM2. (LDS-resident, unchanged)
// ---------------------------------------------------------------------------
__global__ __launch_bounds__(512, 1) void rec_kernel(
    const _Float16* __restrict__ whhp0, const _Float16* __restrict__ whhp1,
    const _Float16* __restrict__ whhp2,
    const _Float16* __restrict__ xgp0, const _Float16* __restrict__ xgp1,
    const _Float16* __restrict__ xgp2,
    float* __restrict__ h_all, float* __restrict__ csave, _Float16* __restrict__ hsave,
    u64* __restrict__ hx,
    int t0, int TC)
{
    __shared__ __align__(16) char smem[151552];
    const int bid = blockIdx.x;
    const int tid = threadIdx.x, w = tid >> 6, l = tid & 63;
    const int ccol = l & 15, crow = (l >> 4) * 4;

    if (bid < 64) {
        // ----- LSTM0, slice block -----
        const int g = bid & 15, s = bid >> 4;
        const int r0 = g * 32;
        _Float16* whhs   = (_Float16*)smem;              // [16][8][64][8] = 128KB
        _Float16* apack  = (_Float16*)(smem + 131072);   // [kc8][rt2][64][8] = 16KB
        _Float16* hstage = (_Float16*)(smem + 147456);   // own slice frag image, 4KB
        u64* apack_u64   = (u64*)apack;
        const int hgroup = w >> 1, rt = w & 1;
        const int sp1 = (s + 1) & 3, sp2 = (s + 2) & 3, sp3 = (s + 3) & 3;

        // w_hh slice -> LDS (gt' = ga*4+hgroup  <->  global gt = ga*16 + s*4 + hgroup)
        for (int v = tid; v < 8192; v += 512) {
            int gtl = v >> 9, off = v & 511;
            int gt = (gtl >> 2) * 16 + s * 4 + (gtl & 3);
            ((u32x4*)whhs)[v] = ((const u32x4*)whhp0)[(size_t)gt * 512 + off];
        }
        float c[4];
        float* cs = csave + ((size_t)bid * 512 + tid) * 4;
        if (t0 == 0) {
#pragma unroll
            for (int i = 0; i < 4; i++) c[i] = 0.f;
            u32x4 z = (u32x4){0u, 0u, 0u, 0u};
            for (int v = tid; v < 1024; v += 512) ((u32x4*)apack)[v] = z;
        } else {
#pragma unroll
            for (int i = 0; i < 4; i++) c[i] = cs[i];
            const u64* hb = &hx[((size_t)(t0 - 1) * 16 + g) * 2048];
            u64 d0 = SENT, d1 = SENT, d2 = SENT, d3 = SENT;
            while (d0 == SENT || d1 == SENT || d2 == SENT || d3 == SENT) {
                if (d0 == SENT) d0 = __hip_atomic_load(&hb[s * 512 + tid],   __ATOMIC_RELAXED, __HIP_MEMORY_SCOPE_AGENT);
                if (d1 == SENT) d1 = __hip_atomic_load(&hb[sp1 * 512 + tid], __ATOMIC_RELAXED, __HIP_MEMORY_SCOPE_AGENT);
                if (d2 == SENT) d2 = __hip_atomic_load(&hb[sp2 * 512 + tid], __ATOMIC_RELAXED, __HIP_MEMORY_SCOPE_AGENT);
                if (d3 == SENT) d3 = __hip_atomic_load(&hb[sp3 * 512 + tid], __ATOMIC_RELAXED, __HIP_MEMORY_SCOPE_AGENT);
            }
            apack_u64[s * 512 + tid]   = d0;
            apack_u64[sp1 * 512 + tid] = d1;
            apack_u64[sp2 * 512 + tid] = d2;
            apack_u64[sp3 * 512 + tid] = d3;
        }
        __syncthreads();

        const _Float16* xgb = xgp0 + ((((size_t)g * 4 + s) * 8 + w) * 64 + l) * 16;
        h8 xcur0 = *(const h8*)&xgb[0];
        h8 xcur1 = *(const h8*)&xgb[8];

        f4 acc[4];
        for (int tc = 0; tc < TC; tc++) {
            const int t = t0 + tc;
            // acc init from xg (bias folded)
#pragma unroll
            for (int q = 0; q < 4; q++) {
                acc[0][q] = (float)xcur0[q];
                acc[1][q] = (float)xcur0[4 + q];
                acc[2][q] = (float)xcur1[q];
                acc[3][q] = (float)xcur1[4 + q];
            }
            // prefetch next xg (covered by MFMA + update)
            h8 xn0 = xcur0, xn1 = xcur1;
            if (tc + 1 < TC) {
                xn0 = *(const h8*)&xgb[(size_t)(tc + 1) * 524288];
                xn1 = *(const h8*)&xgb[(size_t)(tc + 1) * 524288 + 8];
            }
            // gates += h @ w_hh_slice^T
#pragma unroll
            for (int kc = 0; kc < 8; kc++) {
                h8 a = *(const h8*)&apack[((kc * 2 + rt) * 64 + l) * 8];
#pragma unroll
                for (int ga = 0; ga < 4; ga++) {
                    h8 b = *(const h8*)&whhs[(((ga * 4 + hgroup) * 8 + kc) * 64 + l) * 8];
                    acc[ga] = __builtin_amdgcn_mfma_f32_16x16x32_f16(a, b, acc[ga], 0, 0, 0);
                }
            }
            // cell update (all 4 gates in-register)
#pragma unroll
            for (int q = 0; q < 4; q++) {
                float gi = acc[0][q], gf = acc[1][q], gg = acc[2][q], go = acc[3][q];
                float cn = sigm(gf) * c[q] + sigm(gi) * tanhf_(gg);
                c[q] = cn;
                float hv = sigm(go) * tanhf_(cn);
                int row = rt * 16 + crow + q;
                int hcol = hgroup * 16 + ccol;
                if (t == 127) {
                    h_all[(size_t)(r0 + row) * 384 + s * 64 + hcol] = hv;
                } else {
                    int lane2 = (((hcol & 31) >> 3) << 4) | (row & 15);
                    hstage[(((hcol >> 5) * 2 + rt) * 64 + lane2) * 8 + (l & 7)] = (_Float16)hv;
                }
            }
            xcur0 = xn0; xcur1 = xn1;
            __syncthreads();   // B1: hstage complete; all apack MFMA reads done
            if (t < 127) {
                // publish own slice (1 u64/thread, relaxed) + own-copy to apack
                u64 hval = ((u64*)hstage)[tid];
                __hip_atomic_store(&hx[(((size_t)t * 16 + g) * 4 + s) * 512 + tid], hval,
                                   __ATOMIC_RELAXED, __HIP_MEMORY_SCOPE_AGENT);
                apack_u64[s * 512 + tid] = hval;
                // sentinel-poll peer data directly (no flags, no B2)
                const u64* hxs = &hx[(((size_t)t * 16 + g) * 4) * 512];
                u64 v1 = SENT, v2 = SENT, v3 = SENT;
                while (v1 == SENT || v2 == SENT || v3 == SENT) {
                    if (v1 == SENT) v1 = __hip_atomic_load(&hxs[sp1 * 512 + tid], __ATOMIC_RELAXED, __HIP_MEMORY_SCOPE_AGENT);
                    if (v2 == SENT) v2 = __hip_atomic_load(&hxs[sp2 * 512 + tid], __ATOMIC_RELAXED, __HIP_MEMORY_SCOPE_AGENT);
                    if (v3 == SENT) v3 = __hip_atomic_load(&hxs[sp3 * 512 + tid], __ATOMIC_RELAXED, __HIP_MEMORY_SCOPE_AGENT);
                }
                apack_u64[sp1 * 512 + tid] = v1;
                apack_u64[sp2 * 512 + tid] = v2;
                apack_u64[sp3 * 512 + tid] = v3;
                __syncthreads();   // B3: apack = full h(t) ready
            }
        }
        if (t0 + TC < 128) {
#pragma unroll
            for (int i = 0; i < 4; i++) cs[i] = c[i];
        }
    } else {
        // ----- LSTM1 / LSTM2 (LDS-resident, unchanged) -----
        const int m = (bid < 72) ? 1 : 2;
        const int lb = (bid - 64) & 7;
        const int r0 = lb * 64;
        const int colb = (m == 1) ? 256 : 320;
        const _Float16* whhp = (m == 1) ? whhp1 : whhp2;
        const _Float16* xgp  = (m == 1) ? xgp1 : xgp2;
        _Float16* whhs = (_Float16*)smem;                 // 32 KB
        _Float16* apkA = (_Float16*)(smem + 32768);       // 8 KB
        _Float16* apkB = (_Float16*)(smem + 40960);       // 8 KB
        const int rh = w >> 2, ht = w & 3;
        float c[8];
        h8 xbuf[4];
        float* cs = csave + 131072 + (((size_t)(bid - 64)) * 512 + tid) * 8;
        for (int v = tid; v < 2048; v += 512) ((u32x4*)whhs)[v] = ((const u32x4*)whhp)[v];
        if (t0 == 0) {
#pragma unroll
            for (int i = 0; i < 8; i++) c[i] = 0.f;
            u32x4 z = (u32x4){0u, 0u, 0u, 0u};
            for (int v = tid; v < 512; v += 512) ((u32x4*)apkA)[v] = z;
        } else {
#pragma unroll
            for (int i = 0; i < 8; i++) c[i] = cs[i];
            const u32x4* hsrc = (const u32x4*)(hsave + (size_t)(bid - 64) * 4096);
            for (int v = tid; v < 512; v += 512) ((u32x4*)apkA)[v] = hsrc[v];
        }
        __syncthreads();

        const size_t xbase = ((size_t)lb * 8 + w) * 4 * 512 + (size_t)l * 8;
#pragma unroll
        for (int fp = 0; fp < 4; fp++)
            xbuf[fp] = *(const h8*)&xgp[xbase + (size_t)fp * 512];

        f4 acc[2][4];
        for (int tc = 0; tc < TC; tc++) {
            _Float16* cur = (tc & 1) ? apkB : apkA;
            _Float16* nxt = (tc & 1) ? apkA : apkB;
#pragma unroll
            for (int rr = 0; rr < 2; rr++)
#pragma unroll
            for (int gp = 0; gp < 2; gp++) {
                int fp = rr * 2 + gp;
#pragma unroll
                for (int q = 0; q < 4; q++) {
                    acc[rr][2 * gp][q]     = (float)xbuf[fp][q];
                    acc[rr][2 * gp + 1][q] = (float)xbuf[fp][4 + q];
                }
            }
            if (tc + 1 < TC) {
                size_t nb = xbase + (size_t)(tc + 1) * 8 * 8 * 4 * 512;
#pragma unroll
                for (int fp = 0; fp < 4; fp++)
                    xbuf[fp] = *(const h8*)&xgp[nb + (size_t)fp * 512];
            }
#pragma unroll
            for (int kc = 0; kc < 2; kc++) {
                h8 a0 = *(const h8*)&cur[(((rh * 2 + 0) * 2 + kc) * 64 + l) * 8];
                h8 a1 = *(const h8*)&cur[(((rh * 2 + 1) * 2 + kc) * 64 + l) * 8];
#pragma unroll
                for (int ga = 0; ga < 4; ga++) {
                    int gt = ga * 4 + ht;
                    h8 b = *(const h8*)&whhs[((gt * 2 + kc) * 64 + l) * 8];
                    acc[0][ga] = __builtin_amdgcn_mfma_f32_16x16x32_f16(a0, b, acc[0][ga], 0, 0, 0);
                    acc[1][ga] = __builtin_amdgcn_mfma_f32_16x16x32_f16(a1, b, acc[1][ga], 0, 0, 0);
                }
            }
            const int t = t0 + tc;
#pragma unroll
            for (int rr = 0; rr < 2; rr++)
#pragma unroll
            for (int q = 0; q < 4; q++) {
                int idx = rr * 4 + q;
                float gi = acc[rr][0][q];
                float gf = acc[rr][1][q];
                float gg = acc[rr][2][q];
                float go = acc[rr][3][q];
                float cn = sigm(gf) * c[idx] + sigm(gi) * tanhf_(gg);
                c[idx] = cn;
                float hv = sigm(go) * tanhf_(cn);
                int row = (rh * 2 + rr) * 16 + crow + q;
                int hcol = ht * 16 + ccol;
                if (t == 127) h_all[(size_t)(r0 + row) * 384 + colb + hcol] = hv;
                int kch = ht >> 1;
                int sub = (ht & 1) * 2 + (ccol >> 3);
                nxt[(((row >> 4) * 2 + kch) * 64 + sub * 16 + (row & 15)) * 8 + (ccol & 7)] = (_Float16)hv;
            }
            __syncthreads();
        }
        if (t0 + TC < 128) {
#pragma unroll
            for (int i = 0; i < 8; i++) cs[i] = c[i];
            u32x4* hdst = (u32x4*)(hsave + (size_t)(bid - 64) * 4096);
            const u32x4* src = (const u32x4*)((TC & 1) ? apkB : apkA);
            for (int v = tid; v < 512; v += 512) hdst[v] = src[v];
        }
    }
}

// ---------------------------------------------------------------------------
// MLP head (unchanged — verified)
// ---------------------------------------------------------------------------
__global__ __launch_bounds__(512) void mlp_kernel(const float* __restrict__ h_all,
                                                  const float* __restrict__ w1,
                                                  const float* __restrict__ b1,
                                                  const float* __restrict__ w2,
                                                  const float* __restrict__ b2,
                                                  float* __restrict__ out)
{
    __shared__ float w1s[64 * 385];
    __shared__ float hs[8 * 384];
    int tid = threadIdx.x;
    for (int idx = tid; idx < 64 * 384; idx += 512) {
        int j = idx / 384, k = idx - j * 384;
        w1s[j * 385 + k] = w1[idx];
    }
    int r0 = blockIdx.x * 8;
    for (int idx = tid; idx < 8 * 384; idx += 512) hs[idx] = h_all[(size_t)r0 * 384 + idx];
    __syncthreads();

    int w = tid >> 6, j = tid & 63;
    float accv = b1[j];
    const float* hrow = &hs[w * 384];
    for (int k = 0; k < 384; k++) accv = fmaf(hrow[k], w1s[j * 385 + k], accv);
    float hid = fmaxf(accv, 0.f);
    float v = hid * w2[j];
#pragma unroll
    for (int off = 32; off >= 1; off >>= 1) v += __shfl_xor(v, off, 64);
    if (j == 0) out[r0 + w] = v + b2[0];
}

// ---------------------------------------------------------------------------
extern "C" void kernel_launch(void* const* d_in, const int* in_sizes, int n_in,
                              void* d_out, int out_size, void* d_ws, size_t ws_size,
                              hipStream_t stream)
{
    const float* x0   = (const float*)d_in[0];
    const float* x1   = (const float*)d_in[1];
    const float* x2   = (const float*)d_in[2];
    const float* wih0 = (const float*)d_in[3];
    const float* whh0 = (const float*)d_in[4];
    const float* bih0 = (const float*)d_in[5];
    const float* bhh0 = (const float*)d_in[6];
    const float* wih1 = (const float*)d_in[7];
    const float* whh1 = (const float*)d_in[8];
    const float* bih1 = (const float*)d_in[9];
    const float* bhh1 = (const float*)d_in[10];
    const float* wih2 = (const float*)d_in[11];
    const float* whh2 = (const float*)d_in[12];
    const float* bih2 = (const float*)d_in[13];
    const float* bhh2 = (const float*)d_in[14];
    const float* w1   = (const float*)d_in[15];
    const float* b1   = (const float*)d_in[16];
    const float* w2   = (const float*)d_in[17];
    const float* b2   = (const float*)d_in[18];

    char* ws = (char*)d_ws;
    size_t off = 0;
    auto alloc = [&](size_t bytes) { size_t o = off; off = (off + bytes + 255) & ~255ULL; return o; };
    size_t o_wihp0 = alloc(655360);
    size_t o_whhp0 = alloc(524288);
    size_t o_wihp1 = alloc(49152);
    size_t o_whhp1 = alloc(32768);
    size_t o_wihp2 = alloc(32768);
    size_t o_whhp2 = alloc(32768);
    size_t o_bias  = alloc(6144);
    size_t o_hall  = alloc(786432);
    size_t o_csave = alloc(786432);
    size_t o_hsave = alloc(131072);
    size_t o_hx    = alloc(33554432);   // hx[128][16][4][512] u64 (4KB per slice)
    size_t fixed = off;

    int TC = 128;
    while (TC > 1 && fixed + (size_t)TC * 1572864ULL + 1024 > ws_size) TC >>= 1;
    size_t o_xgp0 = alloc((size_t)TC * 1048576ULL);
    size_t o_xgp1 = alloc((size_t)TC * 262144ULL);
    size_t o_xgp2 = alloc((size_t)TC * 262144ULL);

    _Float16* wihp0 = (_Float16*)(ws + o_wihp0);
    _Float16* whhp0 = (_Float16*)(ws + o_whhp0);
    _Float16* wihp1 = (_Float16*)(ws + o_wihp1);
    _Float16* whhp1 = (_Float16*)(ws + o_whhp1);
    _Float16* wihp2 = (_Float16*)(ws + o_wihp2);
    _Float16* whhp2 = (_Float16*)(ws + o_whhp2);
    float*    biasc = (float*)(ws + o_bias);
    float*    hall  = (float*)(ws + o_hall);
    float*    csave = (float*)(ws + o_csave);
    _Float16* hsave = (_Float16*)(ws + o_hsave);
    u64*      hx    = (u64*)(ws + o_hx);
    _Float16* xgp0  = (_Float16*)(ws + o_xgp0);
    _Float16* xgp1  = (_Float16*)(ws + o_xgp1);
    _Float16* xgp2  = (_Float16*)(ws + o_xgp2);

    // sentinel-fill hx: 0xFF pattern = f16 NaN quad, unreachable by real h
    hipMemsetAsync(ws + o_hx, 0xFF, 33554432, stream);

    pack_all<<<330, 256, 0, stream>>>(wih0, whh0, wih1, whh1, wih2, whh2,
                                      bih0, bhh0, bih1, bhh1, bih2, bhh2,
                                      wihp0, whhp0, wihp1, whhp1, wihp2, whhp2, biasc);

    for (int t0 = 0; t0 < 128; t0 += TC) {
        xg_kernel<<<24 * TC, 512, 0, stream>>>(x0, x1, x2, wihp0, wihp1, wihp2, biasc,
                                               xgp0, xgp1, xgp2, t0, TC);
        rec_kernel<<<80, 512, 0, stream>>>(whhp0, whhp1, whhp2, xgp0, xgp1, xgp2,
                                           hall, csave, hsave, hx, t0, TC);
    }

    mlp_kernel<<<64, 512, 0, stream>>>(hall, w1, b1, w2, b2, (float*)d_out);
}